// Round 2
// baseline (5150.336 us; speedup 1.0000x reference)
//
#include <hip/hip_runtime.h>
#include <hip/hip_bf16.h>
#include <math.h>

// All reference tensors are jnp.float32 -> device buffers are float32.

#define B_ 2
#define L_ 2048
#define DM_ 1024
#define DI_ 2048
#define NS_ 16
#define DTR_ 128
#define XPN_ 160   // DTR + 2*NS

// ---------------- generic tiled GEMM: C = A @ B^T ----------------
// A: [M,K] row-major (lda), B: [N,K] row-major (ldb), C: [M,N] (ldc)
// 128x128 block tile, 256 threads, 8x8 per thread, K-tile 16.
enum { EP_PLAIN = 0, EP_SOFTPLUS = 1 };

template <int EPI>
__global__ __launch_bounds__(256) void gemm_abt(
    const float* __restrict__ A, const float* __restrict__ B, float* __restrict__ C,
    const float* __restrict__ bias, int M, int N, int K, int lda, int ldb, int ldc)
{
    __shared__ float As[16][128 + 4];
    __shared__ float Bs[16][128 + 4];
    const int tid = threadIdx.x;
    const int tx = tid & 15, ty = tid >> 4;
    const int row0 = blockIdx.y * 128, col0 = blockIdx.x * 128;

    float acc[8][8];
#pragma unroll
    for (int i = 0; i < 8; ++i)
#pragma unroll
        for (int j = 0; j < 8; ++j) acc[i][j] = 0.f;

    for (int k0 = 0; k0 < K; k0 += 16) {
#pragma unroll
        for (int i = 0; i < 8; ++i) {
            int idx = tid + i * 256;          // 0..2047 = 128 rows x 16 cols
            int r = idx >> 4, c = idx & 15;
            int gr = row0 + r;
            float v = 0.f;
            if (gr < M) v = A[(long)gr * lda + (k0 + c)];
            As[c][r] = v;
        }
#pragma unroll
        for (int i = 0; i < 8; ++i) {
            int idx = tid + i * 256;
            int r = idx >> 4, c = idx & 15;
            int gr = col0 + r;
            float v = 0.f;
            if (gr < N) v = B[(long)gr * ldb + (k0 + c)];
            Bs[c][r] = v;
        }
        __syncthreads();
#pragma unroll
        for (int k = 0; k < 16; ++k) {
            float a[8], b[8];
#pragma unroll
            for (int i = 0; i < 8; ++i) a[i] = As[k][ty * 8 + i];
#pragma unroll
            for (int i = 0; i < 8; ++i) b[i] = Bs[k][tx * 8 + i];
#pragma unroll
            for (int i = 0; i < 8; ++i)
#pragma unroll
                for (int j = 0; j < 8; ++j) acc[i][j] += a[i] * b[j];
        }
        __syncthreads();
    }

#pragma unroll
    for (int i = 0; i < 8; ++i) {
        int gr = row0 + ty * 8 + i;
        if (gr >= M) continue;
#pragma unroll
        for (int j = 0; j < 8; ++j) {
            int gc = col0 + tx * 8 + j;
            if (gc >= N) continue;
            float v = acc[i][j];
            if (EPI == EP_SOFTPLUS) {
                v += bias[gc];
                v = (v > 20.f) ? v : log1pf(expf(v));
            }
            C[(long)gr * ldc + gc] = v;
        }
    }
}

// ---------------- causal depthwise conv(4) + bias + SiLU ----------------
// xz: [B*L, 2*DI] fp32 (xb = cols 0..DI-1). U: [B*L, DI] fp32.
__global__ __launch_bounds__(256) void conv_silu(
    const float* __restrict__ xz, const float* __restrict__ w,
    const float* __restrict__ bc, float* __restrict__ U)
{
    int idx = blockIdx.x * 256 + threadIdx.x;       // (b*L + t)*DI + d
    if (idx >= B_ * L_ * DI_) return;
    int d = idx & (DI_ - 1);
    int bt = idx >> 11;                             // DI_ = 2^11
    int t = bt & (L_ - 1);
    float s = bc[d];
#pragma unroll
    for (int j = 0; j < 4; ++j) {
        int tt = t - 3 + j;
        if (tt >= 0)
            s += w[d * 4 + j] * xz[((long)(bt - t + tt)) * (2 * DI_) + d];
    }
    U[idx] = s / (1.f + expf(-s));                  // silu
}

// ---------------- sequential selective scan + gating ----------------
// thread per channel d; 16 states in registers; B/C staged in LDS (dbuf).
// Y written into xz cols 0..DI-1 (xb half is dead after conv).
__global__ __launch_bounds__(256) void scan_kernel(
    const float* __restrict__ U, const float* __restrict__ DT,
    const float* __restrict__ XDBL, const float* __restrict__ XZ,
    const float* __restrict__ A_log, const float* __restrict__ Dp,
    float* __restrict__ Y)
{
    const int b = blockIdx.x >> 3;                  // 8 blocks per batch
    const int d = ((blockIdx.x & 7) << 8) + threadIdx.x;
    float Ad[NS_], h[NS_];
#pragma unroll
    for (int n = 0; n < NS_; ++n) {
        Ad[n] = -expf(A_log[d * NS_ + n]);
        h[n] = 0.f;
    }
    const float Dd = Dp[d];
    __shared__ float sBC[2][2 * NS_];
    const long base0 = (long)b * L_;
    for (int t = 0; t < L_; ++t) {
        const long bt = base0 + t;
        const int buf = t & 1;
        if (threadIdx.x < 2 * NS_)
            sBC[buf][threadIdx.x] = XDBL[bt * XPN_ + DTR_ + threadIdx.x];
        __syncthreads();
        const float u = U[bt * DI_ + d];
        const float dt = DT[bt * DI_ + d];
        const float du = dt * u;
        float y = 0.f;
#pragma unroll
        for (int n = 0; n < NS_; ++n) {
            h[n] = expf(dt * Ad[n]) * h[n] + du * sBC[buf][n];
            y += h[n] * sBC[buf][NS_ + n];
        }
        const float z = XZ[bt * (2 * DI_) + DI_ + d];
        const float sz = z / (1.f + expf(-z));
        Y[bt * (2 * DI_) + d] = (y + u * Dd) * sz;
    }
}

extern "C" void kernel_launch(void* const* d_in, const int* in_sizes, int n_in,
                              void* d_out, int out_size, void* d_ws, size_t ws_size,
                              hipStream_t stream)
{
    const float* x        = (const float*)d_in[0];
    const float* in_proj  = (const float*)d_in[1];
    const float* conv_w   = (const float*)d_in[2];
    const float* conv_b   = (const float*)d_in[3];
    const float* x_proj   = (const float*)d_in[4];
    const float* dt_proj  = (const float*)d_in[5];
    const float* dt_projb = (const float*)d_in[6];
    const float* A_log    = (const float*)d_in[7];
    const float* Dp       = (const float*)d_in[8];
    const float* out_proj = (const float*)d_in[9];

    const int M = B_ * L_;                       // 4096
    float* XZ   = (float*)d_ws;                  // [M, 2*DI]   64 MB
    float* U    = XZ + (size_t)M * 2 * DI_;      // [M, DI]     32 MB
    float* XDBL = U + (size_t)M * DI_;           // [M, 160]    2.5 MB
    float* DT   = XDBL + (size_t)M * XPN_;       // [M, DI]     32 MB

    // 1) xz = x @ in_proj^T   [4096 x 4096], K=1024
    gemm_abt<EP_PLAIN><<<dim3(32, 32), 256, 0, stream>>>(
        x, in_proj, XZ, nullptr, M, 2 * DI_, DM_, DM_, DM_, 2 * DI_);

    // 2) u = silu(conv(xb) + b)
    conv_silu<<<(M * DI_ + 255) / 256, 256, 0, stream>>>(XZ, conv_w, conv_b, U);

    // 3) x_dbl = u @ x_proj^T   [4096 x 160], K=2048
    gemm_abt<EP_PLAIN><<<dim3(2, 32), 256, 0, stream>>>(
        U, x_proj, XDBL, nullptr, M, XPN_, DI_, DI_, DI_, XPN_);

    // 4) dt = softplus(x_dbl[:, :128] @ dt_proj^T + dt_proj_b)   [4096 x 2048], K=128
    gemm_abt<EP_SOFTPLUS><<<dim3(16, 32), 256, 0, stream>>>(
        XDBL, dt_proj, DT, dt_projb, M, DI_, DTR_, XPN_, DTR_, DI_);

    // 5) selective scan + D-skip + z-gating; Y overwrites xz cols 0..DI-1
    scan_kernel<<<16, 256, 0, stream>>>(U, DT, XDBL, XZ, A_log, Dp, XZ);

    // 6) out = y @ out_proj^T   [4096 x 1024], K=2048 (A = XZ with lda=4096)
    gemm_abt<EP_PLAIN><<<dim3(8, 32), 256, 0, stream>>>(
        XZ, out_proj, (float*)d_out, nullptr, M, DM_, DI_, 2 * DI_, DI_, DM_);
}

// Round 3
// 2370.955 us; speedup vs baseline: 2.1723x; 2.1723x over previous
//
#include <hip/hip_runtime.h>
#include <hip/hip_bf16.h>
#include <math.h>

// All reference tensors are jnp.float32.

#define B_ 2
#define L_ 2048
#define DM_ 1024
#define DI_ 2048
#define NS_ 16
#define DTR_ 128
#define XPN_ 160   // DTR + 2*NS
#define CH_ 8      // chunks over L
#define CL_ 256    // L / CH_
#define NCH_ 4096  // B_ * DI_

// ---------------- generic tiled GEMM: C = A @ B^T ----------------
enum { EP_PLAIN = 0, EP_SOFTPLUS = 1 };

template <int EPI>
__global__ __launch_bounds__(256) void gemm_abt(
    const float* __restrict__ A, const float* __restrict__ B, float* __restrict__ C,
    const float* __restrict__ bias, int M, int N, int K, int lda, int ldb, int ldc)
{
    __shared__ float As[16][128 + 4];
    __shared__ float Bs[16][128 + 4];
    const int tid = threadIdx.x;
    const int tx = tid & 15, ty = tid >> 4;
    const int row0 = blockIdx.y * 128, col0 = blockIdx.x * 128;

    float acc[8][8];
#pragma unroll
    for (int i = 0; i < 8; ++i)
#pragma unroll
        for (int j = 0; j < 8; ++j) acc[i][j] = 0.f;

    for (int k0 = 0; k0 < K; k0 += 16) {
#pragma unroll
        for (int i = 0; i < 8; ++i) {
            int idx = tid + i * 256;
            int r = idx >> 4, c = idx & 15;
            int gr = row0 + r;
            float v = 0.f;
            if (gr < M) v = A[(long)gr * lda + (k0 + c)];
            As[c][r] = v;
        }
#pragma unroll
        for (int i = 0; i < 8; ++i) {
            int idx = tid + i * 256;
            int r = idx >> 4, c = idx & 15;
            int gr = col0 + r;
            float v = 0.f;
            if (gr < N) v = B[(long)gr * ldb + (k0 + c)];
            Bs[c][r] = v;
        }
        __syncthreads();
#pragma unroll
        for (int k = 0; k < 16; ++k) {
            float a[8], b[8];
#pragma unroll
            for (int i = 0; i < 8; ++i) a[i] = As[k][ty * 8 + i];
#pragma unroll
            for (int i = 0; i < 8; ++i) b[i] = Bs[k][tx * 8 + i];
#pragma unroll
            for (int i = 0; i < 8; ++i)
#pragma unroll
                for (int j = 0; j < 8; ++j) acc[i][j] += a[i] * b[j];
        }
        __syncthreads();
    }

#pragma unroll
    for (int i = 0; i < 8; ++i) {
        int gr = row0 + ty * 8 + i;
        if (gr >= M) continue;
#pragma unroll
        for (int j = 0; j < 8; ++j) {
            int gc = col0 + tx * 8 + j;
            if (gc >= N) continue;
            float v = acc[i][j];
            if (EPI == EP_SOFTPLUS) {
                v += bias[gc];
                v = (v > 20.f) ? v : log1pf(__expf(v));
            }
            C[(long)gr * ldc + gc] = v;
        }
    }
}

// ---------------- causal depthwise conv(4) + bias + SiLU ----------------
__global__ __launch_bounds__(256) void conv_silu(
    const float* __restrict__ xz, const float* __restrict__ w,
    const float* __restrict__ bc, float* __restrict__ U)
{
    int idx = blockIdx.x * 256 + threadIdx.x;       // (b*L + t)*DI + d
    if (idx >= B_ * L_ * DI_) return;
    int d = idx & (DI_ - 1);
    int bt = idx >> 11;
    int t = bt & (L_ - 1);
    float s = bc[d];
#pragma unroll
    for (int j = 0; j < 4; ++j) {
        int tt = t - 3 + j;
        if (tt >= 0)
            s += w[d * 4 + j] * xz[((long)(bt - t + tt)) * (2 * DI_) + d];
    }
    U[idx] = s / (1.f + __expf(-s));                // silu
}

// ---------------- Pass A: per-chunk local scan ----------------
// grid (dblk=8, chunk=8, b=2) x 256 threads. Each thread: one channel d,
// scans CL_=256 steps from h=0 in tiles of 8. Writes partial y into XZ's
// xb half, cumulative dt over DT, and chunk-final h into HEND[c][n][ch].
__global__ __launch_bounds__(256) void scan_chunk(
    const float* __restrict__ U, float* __restrict__ DT,
    const float* __restrict__ XDBL, const float* __restrict__ A_log,
    float* __restrict__ XZ, float* __restrict__ HEND)
{
    const int d = blockIdx.x * 256 + threadIdx.x;
    const int chunk = blockIdx.y;
    const int b = blockIdx.z;
    const int channel = b * DI_ + d;
    const long t0 = (long)b * L_ + chunk * CL_;

    float An[NS_], h[NS_];
#pragma unroll
    for (int n = 0; n < NS_; ++n) {
        An[n] = -__expf(A_log[d * NS_ + n]);
        h[n] = 0.f;
    }
    float sum_dt = 0.f;
    __shared__ float sB[8][NS_], sC[8][NS_];

    for (int tt0 = 0; tt0 < CL_; tt0 += 8) {
        const long bt0 = t0 + tt0;
        // stage B,C for 8 steps: 8*32 = 256 values
        {
            int i = threadIdx.x >> 5, j = threadIdx.x & 31;
            float v = XDBL[(bt0 + i) * XPN_ + DTR_ + j];
            if (j < NS_) sB[i][j] = v; else sC[i][j - NS_] = v;
        }
        __syncthreads();
        float u8[8], dt8[8], y8[8], cum8[8];
#pragma unroll
        for (int i = 0; i < 8; ++i) u8[i] = U[(bt0 + i) * DI_ + d];
#pragma unroll
        for (int i = 0; i < 8; ++i) dt8[i] = DT[(bt0 + i) * DI_ + d];
#pragma unroll
        for (int i = 0; i < 8; ++i) {
            const float dt = dt8[i];
            sum_dt += dt;
            cum8[i] = sum_dt;
            const float du = dt * u8[i];
            float y = 0.f;
#pragma unroll
            for (int n = 0; n < NS_; ++n) {
                h[n] = __expf(An[n] * dt) * h[n] + du * sB[i][n];
                y += h[n] * sC[i][n];
            }
            y8[i] = y;
        }
#pragma unroll
        for (int i = 0; i < 8; ++i) XZ[(bt0 + i) * (2 * DI_) + d] = y8[i];
#pragma unroll
        for (int i = 0; i < 8; ++i) DT[(bt0 + i) * DI_ + d] = cum8[i];
        __syncthreads();
    }
#pragma unroll
    for (int n = 0; n < NS_; ++n)
        HEND[(chunk * NS_ + n) * NCH_ + channel] = h[n];
}

// ---------------- Pass B: combine chunk states (in-place) ----------------
// One thread per channel. After this, HEND[c][n][ch] holds h_START of chunk c.
__global__ __launch_bounds__(256) void scan_mid(
    const float* __restrict__ DT, const float* __restrict__ A_log,
    float* __restrict__ HST)
{
    const int channel = blockIdx.x * 256 + threadIdx.x;
    const int b = channel / DI_, d = channel % DI_;
    float An[NS_], h0[NS_];
#pragma unroll
    for (int n = 0; n < NS_; ++n) {
        An[n] = -__expf(A_log[d * NS_ + n]);
        h0[n] = 0.f;
    }
    for (int c = 0; c < CH_; ++c) {
        float he[NS_];
#pragma unroll
        for (int n = 0; n < NS_; ++n) {
            he[n] = HST[(c * NS_ + n) * NCH_ + channel];
            HST[(c * NS_ + n) * NCH_ + channel] = h0[n];
        }
        if (c < CH_ - 1) {
            const float S = DT[((long)b * L_ + c * CL_ + CL_ - 1) * DI_ + d];
#pragma unroll
            for (int n = 0; n < NS_; ++n)
                h0[n] = __expf(An[n] * S) * h0[n] + he[n];
        }
    }
}

// ---------------- Pass C: correction + D-skip + z-gating ----------------
// grid (dblk=8, chunk=8, b=2) x 256; loops t over the chunk in tiles of 8.
__global__ __launch_bounds__(256) void scan_fix(
    const float* __restrict__ U, const float* __restrict__ DT,
    const float* __restrict__ XDBL, const float* __restrict__ A_log,
    const float* __restrict__ Dp, const float* __restrict__ HST,
    float* __restrict__ XZ)
{
    const int d = blockIdx.x * 256 + threadIdx.x;
    const int chunk = blockIdx.y;
    const int b = blockIdx.z;
    const int channel = b * DI_ + d;
    const long t0 = (long)b * L_ + chunk * CL_;

    float An[NS_], h0[NS_];
#pragma unroll
    for (int n = 0; n < NS_; ++n) {
        An[n] = -__expf(A_log[d * NS_ + n]);
        h0[n] = HST[(chunk * NS_ + n) * NCH_ + channel];
    }
    const float Dd = Dp[d];
    __shared__ float sC[8][NS_];

    for (int tt0 = 0; tt0 < CL_; tt0 += 8) {
        const long bt0 = t0 + tt0;
        if (threadIdx.x < 128) {
            int i = threadIdx.x >> 4, n = threadIdx.x & 15;
            sC[i][n] = XDBL[(bt0 + i) * XPN_ + DTR_ + NS_ + n];
        }
        __syncthreads();
        float cum8[8], yp8[8], u8[8], z8[8];
#pragma unroll
        for (int i = 0; i < 8; ++i) cum8[i] = DT[(bt0 + i) * DI_ + d];
#pragma unroll
        for (int i = 0; i < 8; ++i) yp8[i] = XZ[(bt0 + i) * (2 * DI_) + d];
#pragma unroll
        for (int i = 0; i < 8; ++i) u8[i] = U[(bt0 + i) * DI_ + d];
#pragma unroll
        for (int i = 0; i < 8; ++i) z8[i] = XZ[(bt0 + i) * (2 * DI_) + DI_ + d];
#pragma unroll
        for (int i = 0; i < 8; ++i) {
            float corr = 0.f;
#pragma unroll
            for (int n = 0; n < NS_; ++n)
                corr += sC[i][n] * __expf(An[n] * cum8[i]) * h0[n];
            const float y = yp8[i] + corr + u8[i] * Dd;
            const float z = z8[i];
            yp8[i] = y * (z / (1.f + __expf(-z)));
        }
#pragma unroll
        for (int i = 0; i < 8; ++i) XZ[(bt0 + i) * (2 * DI_) + d] = yp8[i];
        __syncthreads();
    }
}

extern "C" void kernel_launch(void* const* d_in, const int* in_sizes, int n_in,
                              void* d_out, int out_size, void* d_ws, size_t ws_size,
                              hipStream_t stream)
{
    const float* x        = (const float*)d_in[0];
    const float* in_proj  = (const float*)d_in[1];
    const float* conv_w   = (const float*)d_in[2];
    const float* conv_b   = (const float*)d_in[3];
    const float* x_proj   = (const float*)d_in[4];
    const float* dt_proj  = (const float*)d_in[5];
    const float* dt_projb = (const float*)d_in[6];
    const float* A_log    = (const float*)d_in[7];
    const float* Dp       = (const float*)d_in[8];
    const float* out_proj = (const float*)d_in[9];

    const int M = B_ * L_;                       // 4096
    float* XZ   = (float*)d_ws;                  // [M, 2*DI]   64 MB
    float* U    = XZ + (size_t)M * 2 * DI_;      // [M, DI]     32 MB
    float* XDBL = U + (size_t)M * DI_;           // [M, 160]    2.5 MB
    float* DT   = XDBL + (size_t)M * XPN_;       // [M, DI]     32 MB (cumdt after pass A)
    float* HEND = DT + (size_t)M * DI_;          // [CH][NS][NCH]  2 MB

    // 1) xz = x @ in_proj^T
    gemm_abt<EP_PLAIN><<<dim3(32, 32), 256, 0, stream>>>(
        x, in_proj, XZ, nullptr, M, 2 * DI_, DM_, DM_, DM_, 2 * DI_);

    // 2) u = silu(conv(xb) + b)
    conv_silu<<<(M * DI_ + 255) / 256, 256, 0, stream>>>(XZ, conv_w, conv_b, U);

    // 3) x_dbl = u @ x_proj^T
    gemm_abt<EP_PLAIN><<<dim3(2, 32), 256, 0, stream>>>(
        U, x_proj, XDBL, nullptr, M, XPN_, DI_, DI_, DI_, XPN_);

    // 4) dt = softplus(x_dbl[:, :128] @ dt_proj^T + b)
    gemm_abt<EP_SOFTPLUS><<<dim3(16, 32), 256, 0, stream>>>(
        XDBL, dt_proj, DT, dt_projb, M, DI_, DTR_, XPN_, DTR_, DI_);

    // 5) chunked selective scan
    scan_chunk<<<dim3(8, CH_, B_), 256, 0, stream>>>(U, DT, XDBL, A_log, XZ, HEND);
    scan_mid<<<NCH_ / 256, 256, 0, stream>>>(DT, A_log, HEND);
    scan_fix<<<dim3(8, CH_, B_), 256, 0, stream>>>(U, DT, XDBL, A_log, Dp, HEND, XZ);

    // 6) out = y @ out_proj^T
    gemm_abt<EP_PLAIN><<<dim3(8, 32), 256, 0, stream>>>(
        XZ, out_proj, (float*)d_out, nullptr, M, DM_, DI_, 2 * DI_, DI_, DM_);
}

// Round 4
// 1321.491 us; speedup vs baseline: 3.8974x; 1.7942x over previous
//
#include <hip/hip_runtime.h>
#include <hip/hip_bf16.h>
#include <math.h>

// All reference tensors are jnp.float32.

#define B_ 2
#define L_ 2048
#define DM_ 1024
#define DI_ 2048
#define NS_ 16
#define DTR_ 128
#define XPN_ 160   // DTR + 2*NS
#define CH_ 8      // chunks over L
#define CL_ 256    // L / CH_
#define NCH_ 4096  // B_ * DI_

typedef __attribute__((ext_vector_type(8))) short short8;
typedef __attribute__((ext_vector_type(4))) float f32x4;

__device__ inline unsigned short bfbits(float f) {
    __hip_bfloat16 h = __float2bfloat16(f);
    return *reinterpret_cast<unsigned short*>(&h);
}
__device__ inline float bff(unsigned short u) {
    __hip_bfloat16 h;
    *reinterpret_cast<unsigned short*>(&h) = u;
    return __bfloat162float(h);
}

// ---------------- fp32 -> bf16 hi/lo split (flat) ----------------
__global__ __launch_bounds__(256) void split_flat(
    const float* __restrict__ s, unsigned short* __restrict__ hi,
    unsigned short* __restrict__ lo, int n)
{
    int i = (blockIdx.x * 256 + threadIdx.x) * 4;
    if (i >= n) return;
    float4 v = *(const float4*)(s + i);
    float f[4] = {v.x, v.y, v.z, v.w};
    unsigned short hh[4], ll[4];
#pragma unroll
    for (int c = 0; c < 4; ++c) {
        hh[c] = bfbits(f[c]);
        ll[c] = bfbits(f[c] - bff(hh[c]));
    }
    *(ushort4*)(hi + i) = make_ushort4(hh[0], hh[1], hh[2], hh[3]);
    *(ushort4*)(lo + i) = make_ushort4(ll[0], ll[1], ll[2], ll[3]);
}

// ---------------- strided split: y (cols 0..DI-1 of XZ) ----------------
__global__ __launch_bounds__(256) void split_y(
    const float* __restrict__ XZ, unsigned short* __restrict__ hi,
    unsigned short* __restrict__ lo)
{
    int idx = blockIdx.x * 256 + threadIdx.x;     // over M*DI/4
    int t = idx >> 9;                             // DI_/4 = 512
    int d = (idx & 511) * 4;
    float4 v = *(const float4*)(XZ + (long)t * (2 * DI_) + d);
    float f[4] = {v.x, v.y, v.z, v.w};
    unsigned short hh[4], ll[4];
#pragma unroll
    for (int c = 0; c < 4; ++c) {
        hh[c] = bfbits(f[c]);
        ll[c] = bfbits(f[c] - bff(hh[c]));
    }
    long o = (long)t * DI_ + d;
    *(ushort4*)(hi + o) = make_ushort4(hh[0], hh[1], hh[2], hh[3]);
    *(ushort4*)(lo + o) = make_ushort4(ll[0], ll[1], ll[2], ll[3]);
}

// ---------------- MFMA split-bf16 GEMM: C = A @ B^T ----------------
// A: [M,K] split into Ah/Al bf16 (lda), B: [N,K] split Bh/Bl (ldb), C fp32.
// 128x128 block, 4 waves, each wave 64x64 = 4x4 tiles of 16x16, KT=32.
// M,N must be multiples of 128 (true for both uses). K multiple of 32.
__global__ __launch_bounds__(256) void gemm_mfma(
    const unsigned short* __restrict__ Ah, const unsigned short* __restrict__ Al, int lda,
    const unsigned short* __restrict__ Bh, const unsigned short* __restrict__ Bl, int ldb,
    float* __restrict__ C, int ldc, int K)
{
    __shared__ unsigned short sA[2][128][40];   // [hi/lo][row][k], pad 32->40
    __shared__ unsigned short sB[2][128][40];
    const int tid = threadIdx.x;
    const int lane = tid & 63, wave = tid >> 6;
    const int row0 = blockIdx.y * 128, col0 = blockIdx.x * 128;
    const int wm = (wave & 1) << 6, wn = (wave >> 1) << 6;
    const int m = lane & 15;              // frag row/col within 16
    const int ko = (lane >> 4) << 3;      // k-offset 0,8,16,24

    f32x4 acc[4][4];
    const f32x4 zero = {0.f, 0.f, 0.f, 0.f};
#pragma unroll
    for (int i = 0; i < 4; ++i)
#pragma unroll
        for (int j = 0; j < 4; ++j) acc[i][j] = zero;

    for (int k0 = 0; k0 < K; k0 += 32) {
#pragma unroll
        for (int c = 0; c < 2; ++c) {
            int idx = tid + (c << 8);          // 0..511
            int r = idx >> 2;                  // 0..127
            int col8 = (idx & 3) << 3;         // 0,8,16,24
            *(short8*)&sA[0][r][col8] = *(const short8*)(Ah + (long)(row0 + r) * lda + k0 + col8);
            *(short8*)&sA[1][r][col8] = *(const short8*)(Al + (long)(row0 + r) * lda + k0 + col8);
            *(short8*)&sB[0][r][col8] = *(const short8*)(Bh + (long)(col0 + r) * ldb + k0 + col8);
            *(short8*)&sB[1][r][col8] = *(const short8*)(Bl + (long)(col0 + r) * ldb + k0 + col8);
        }
        __syncthreads();

        short8 ah[4], al[4];
#pragma unroll
        for (int i = 0; i < 4; ++i) {
            ah[i] = *(const short8*)&sA[0][wm + i * 16 + m][ko];
            al[i] = *(const short8*)&sA[1][wm + i * 16 + m][ko];
        }
#pragma unroll
        for (int j = 0; j < 4; ++j) {
            short8 bh = *(const short8*)&sB[0][wn + j * 16 + m][ko];
            short8 bl = *(const short8*)&sB[1][wn + j * 16 + m][ko];
#pragma unroll
            for (int i = 0; i < 4; ++i) {
                acc[i][j] = __builtin_amdgcn_mfma_f32_16x16x32_bf16(ah[i], bh, acc[i][j], 0, 0, 0);
                acc[i][j] = __builtin_amdgcn_mfma_f32_16x16x32_bf16(al[i], bh, acc[i][j], 0, 0, 0);
                acc[i][j] = __builtin_amdgcn_mfma_f32_16x16x32_bf16(ah[i], bl, acc[i][j], 0, 0, 0);
            }
        }
        __syncthreads();
    }

    // C/D layout: col = lane&15, row = (lane>>4)*4 + reg
    const int cr = (lane >> 4) << 2;
#pragma unroll
    for (int i = 0; i < 4; ++i) {
#pragma unroll
        for (int j = 0; j < 4; ++j) {
            int gr = row0 + wm + i * 16 + cr;
            int gc = col0 + wn + j * 16 + m;
#pragma unroll
            for (int r = 0; r < 4; ++r)
                C[(long)(gr + r) * ldc + gc] = acc[i][j][r];
        }
    }
}

// ---------------- vector-ALU tiled GEMM (for the small GEMMs) ----------------
enum { EP_PLAIN = 0, EP_SOFTPLUS = 1 };

template <int EPI>
__global__ __launch_bounds__(256) void gemm_abt(
    const float* __restrict__ A, const float* __restrict__ B, float* __restrict__ C,
    const float* __restrict__ bias, int M, int N, int K, int lda, int ldb, int ldc)
{
    __shared__ float As[16][128 + 4];
    __shared__ float Bs[16][128 + 4];
    const int tid = threadIdx.x;
    const int tx = tid & 15, ty = tid >> 4;
    const int row0 = blockIdx.y * 128, col0 = blockIdx.x * 128;

    float acc[8][8];
#pragma unroll
    for (int i = 0; i < 8; ++i)
#pragma unroll
        for (int j = 0; j < 8; ++j) acc[i][j] = 0.f;

    for (int k0 = 0; k0 < K; k0 += 16) {
#pragma unroll
        for (int i = 0; i < 8; ++i) {
            int idx = tid + i * 256;
            int r = idx >> 4, c = idx & 15;
            int gr = row0 + r;
            float v = 0.f;
            if (gr < M) v = A[(long)gr * lda + (k0 + c)];
            As[c][r] = v;
        }
#pragma unroll
        for (int i = 0; i < 8; ++i) {
            int idx = tid + i * 256;
            int r = idx >> 4, c = idx & 15;
            int gr = col0 + r;
            float v = 0.f;
            if (gr < N) v = B[(long)gr * ldb + (k0 + c)];
            Bs[c][r] = v;
        }
        __syncthreads();
#pragma unroll
        for (int k = 0; k < 16; ++k) {
            float a[8], b[8];
#pragma unroll
            for (int i = 0; i < 8; ++i) a[i] = As[k][ty * 8 + i];
#pragma unroll
            for (int i = 0; i < 8; ++i) b[i] = Bs[k][tx * 8 + i];
#pragma unroll
            for (int i = 0; i < 8; ++i)
#pragma unroll
                for (int j = 0; j < 8; ++j) acc[i][j] += a[i] * b[j];
        }
        __syncthreads();
    }

#pragma unroll
    for (int i = 0; i < 8; ++i) {
        int gr = row0 + ty * 8 + i;
        if (gr >= M) continue;
#pragma unroll
        for (int j = 0; j < 8; ++j) {
            int gc = col0 + tx * 8 + j;
            if (gc >= N) continue;
            float v = acc[i][j];
            if (EPI == EP_SOFTPLUS) {
                v += bias[gc];
                v = (v > 20.f) ? v : log1pf(__expf(v));
            }
            C[(long)gr * ldc + gc] = v;
        }
    }
}

// ---------------- causal depthwise conv(4) + bias + SiLU ----------------
__global__ __launch_bounds__(256) void conv_silu(
    const float* __restrict__ xz, const float* __restrict__ w,
    const float* __restrict__ bc, float* __restrict__ U)
{
    int idx = blockIdx.x * 256 + threadIdx.x;       // (b*L + t)*DI + d
    if (idx >= B_ * L_ * DI_) return;
    int d = idx & (DI_ - 1);
    int bt = idx >> 11;
    int t = bt & (L_ - 1);
    float s = bc[d];
#pragma unroll
    for (int j = 0; j < 4; ++j) {
        int tt = t - 3 + j;
        if (tt >= 0)
            s += w[d * 4 + j] * xz[((long)(bt - t + tt)) * (2 * DI_) + d];
    }
    U[idx] = s / (1.f + __expf(-s));                // silu
}

// ---------------- Pass A: per-chunk local scan ----------------
__global__ __launch_bounds__(256) void scan_chunk(
    const float* __restrict__ U, float* __restrict__ DT,
    const float* __restrict__ XDBL, const float* __restrict__ A_log,
    float* __restrict__ XZ, float* __restrict__ HEND)
{
    const int d = blockIdx.x * 256 + threadIdx.x;
    const int chunk = blockIdx.y;
    const int b = blockIdx.z;
    const int channel = b * DI_ + d;
    const long t0 = (long)b * L_ + chunk * CL_;

    float An[NS_], h[NS_];
#pragma unroll
    for (int n = 0; n < NS_; ++n) {
        An[n] = -__expf(A_log[d * NS_ + n]);
        h[n] = 0.f;
    }
    float sum_dt = 0.f;
    __shared__ float sB[8][NS_], sC[8][NS_];

    for (int tt0 = 0; tt0 < CL_; tt0 += 8) {
        const long bt0 = t0 + tt0;
        {
            int i = threadIdx.x >> 5, j = threadIdx.x & 31;
            float v = XDBL[(bt0 + i) * XPN_ + DTR_ + j];
            if (j < NS_) sB[i][j] = v; else sC[i][j - NS_] = v;
        }
        __syncthreads();
        float u8[8], dt8[8], y8[8], cum8[8];
#pragma unroll
        for (int i = 0; i < 8; ++i) u8[i] = U[(bt0 + i) * DI_ + d];
#pragma unroll
        for (int i = 0; i < 8; ++i) dt8[i] = DT[(bt0 + i) * DI_ + d];
#pragma unroll
        for (int i = 0; i < 8; ++i) {
            const float dt = dt8[i];
            sum_dt += dt;
            cum8[i] = sum_dt;
            const float du = dt * u8[i];
            float y = 0.f;
#pragma unroll
            for (int n = 0; n < NS_; ++n) {
                h[n] = __expf(An[n] * dt) * h[n] + du * sB[i][n];
                y += h[n] * sC[i][n];
            }
            y8[i] = y;
        }
#pragma unroll
        for (int i = 0; i < 8; ++i) XZ[(bt0 + i) * (2 * DI_) + d] = y8[i];
#pragma unroll
        for (int i = 0; i < 8; ++i) DT[(bt0 + i) * DI_ + d] = cum8[i];
        __syncthreads();
    }
#pragma unroll
    for (int n = 0; n < NS_; ++n)
        HEND[(chunk * NS_ + n) * NCH_ + channel] = h[n];
}

// ---------------- Pass B: combine chunk states (in-place) ----------------
__global__ __launch_bounds__(256) void scan_mid(
    const float* __restrict__ DT, const float* __restrict__ A_log,
    float* __restrict__ HST)
{
    const int channel = blockIdx.x * 256 + threadIdx.x;
    const int b = channel / DI_, d = channel % DI_;
    float An[NS_], h0[NS_];
#pragma unroll
    for (int n = 0; n < NS_; ++n) {
        An[n] = -__expf(A_log[d * NS_ + n]);
        h0[n] = 0.f;
    }
    for (int c = 0; c < CH_; ++c) {
        float he[NS_];
#pragma unroll
        for (int n = 0; n < NS_; ++n) {
            he[n] = HST[(c * NS_ + n) * NCH_ + channel];
            HST[(c * NS_ + n) * NCH_ + channel] = h0[n];
        }
        if (c < CH_ - 1) {
            const float S = DT[((long)b * L_ + c * CL_ + CL_ - 1) * DI_ + d];
#pragma unroll
            for (int n = 0; n < NS_; ++n)
                h0[n] = __expf(An[n] * S) * h0[n] + he[n];
        }
    }
}

// ---------------- Pass C: correction + D-skip + z-gating ----------------
__global__ __launch_bounds__(256) void scan_fix(
    const float* __restrict__ U, const float* __restrict__ DT,
    const float* __restrict__ XDBL, const float* __restrict__ A_log,
    const float* __restrict__ Dp, const float* __restrict__ HST,
    float* __restrict__ XZ)
{
    const int d = blockIdx.x * 256 + threadIdx.x;
    const int chunk = blockIdx.y;
    const int b = blockIdx.z;
    const int channel = b * DI_ + d;
    const long t0 = (long)b * L_ + chunk * CL_;

    float An[NS_], h0[NS_];
#pragma unroll
    for (int n = 0; n < NS_; ++n) {
        An[n] = -__expf(A_log[d * NS_ + n]);
        h0[n] = HST[(chunk * NS_ + n) * NCH_ + channel];
    }
    const float Dd = Dp[d];
    __shared__ float sC[8][NS_];

    for (int tt0 = 0; tt0 < CL_; tt0 += 8) {
        const long bt0 = t0 + tt0;
        if (threadIdx.x < 128) {
            int i = threadIdx.x >> 4, n = threadIdx.x & 15;
            sC[i][n] = XDBL[(bt0 + i) * XPN_ + DTR_ + NS_ + n];
        }
        __syncthreads();
        float cum8[8], yp8[8], u8[8], z8[8];
#pragma unroll
        for (int i = 0; i < 8; ++i) cum8[i] = DT[(bt0 + i) * DI_ + d];
#pragma unroll
        for (int i = 0; i < 8; ++i) yp8[i] = XZ[(bt0 + i) * (2 * DI_) + d];
#pragma unroll
        for (int i = 0; i < 8; ++i) u8[i] = U[(bt0 + i) * DI_ + d];
#pragma unroll
        for (int i = 0; i < 8; ++i) z8[i] = XZ[(bt0 + i) * (2 * DI_) + DI_ + d];
#pragma unroll
        for (int i = 0; i < 8; ++i) {
            float corr = 0.f;
#pragma unroll
            for (int n = 0; n < NS_; ++n)
                corr += sC[i][n] * __expf(An[n] * cum8[i]) * h0[n];
            const float y = yp8[i] + corr + u8[i] * Dd;
            const float z = z8[i];
            yp8[i] = y * (z / (1.f + __expf(-z)));
        }
#pragma unroll
        for (int i = 0; i < 8; ++i) XZ[(bt0 + i) * (2 * DI_) + d] = yp8[i];
        __syncthreads();
    }
}

extern "C" void kernel_launch(void* const* d_in, const int* in_sizes, int n_in,
                              void* d_out, int out_size, void* d_ws, size_t ws_size,
                              hipStream_t stream)
{
    const float* x        = (const float*)d_in[0];
    const float* in_proj  = (const float*)d_in[1];
    const float* conv_w   = (const float*)d_in[2];
    const float* conv_b   = (const float*)d_in[3];
    const float* x_proj   = (const float*)d_in[4];
    const float* dt_proj  = (const float*)d_in[5];
    const float* dt_projb = (const float*)d_in[6];
    const float* A_log    = (const float*)d_in[7];
    const float* Dp       = (const float*)d_in[8];
    const float* out_proj = (const float*)d_in[9];

    const int M = B_ * L_;                       // 4096
    float* XZ   = (float*)d_ws;                  // [M, 2*DI]   64 MB
    float* U    = XZ + (size_t)M * 2 * DI_;      // [M, DI]     32 MB
    float* XDBL = U + (size_t)M * DI_;           // [M, 160]    2.5 MB
    float* DT   = XDBL + (size_t)M * XPN_;       // [M, DI]     32 MB
    float* HEND = DT + (size_t)M * DI_;          // 2 MB

    // --- overlays (all inside existing regions, disjoint lifetimes) ---
    const int NX = M * DM_;                      // x / in_proj elems (4.19M)
    const int NO = DM_ * DI_;                    // out_proj elems (2.1M)
    unsigned short* XH = (unsigned short*)U;          // 8.4 MB  (dead before conv writes U)
    unsigned short* XL = XH + NX;                     // 8.4 MB
    unsigned short* WH = (unsigned short*)DT;         // in_proj split (dead before GEMM3 writes DT)
    unsigned short* WL = WH + NX;
    unsigned short* YH = (unsigned short*)U;          // y split (U+XDBL dead after scan_fix)
    unsigned short* YL = YH + (size_t)M * DI_;
    unsigned short* OH = (unsigned short*)DT;         // out_proj split (DT dead after scan_fix)
    unsigned short* OL = OH + NO;

    // 1) split x and in_proj to bf16 hi/lo
    split_flat<<<NX / 1024, 256, 0, stream>>>(x, XH, XL, NX);
    split_flat<<<NX / 1024, 256, 0, stream>>>(in_proj, WH, WL, NX);

    // 2) xz = x @ in_proj^T  (MFMA split-bf16)  [4096 x 4096], K=1024
    gemm_mfma<<<dim3(32, 32), 256, 0, stream>>>(
        XH, XL, DM_, WH, WL, DM_, XZ, 2 * DI_, DM_);

    // 3) u = silu(conv(xb) + b)   (overwrites XH/XL region)
    conv_silu<<<(M * DI_ + 255) / 256, 256, 0, stream>>>(XZ, conv_w, conv_b, U);

    // 4) x_dbl = u @ x_proj^T   [4096 x 160], K=2048
    gemm_abt<EP_PLAIN><<<dim3(2, 32), 256, 0, stream>>>(
        U, x_proj, XDBL, nullptr, M, XPN_, DI_, DI_, DI_, XPN_);

    // 5) dt = softplus(x_dbl[:, :128] @ dt_proj^T + b)  (overwrites WH/WL)
    gemm_abt<EP_SOFTPLUS><<<dim3(16, 32), 256, 0, stream>>>(
        XDBL, dt_proj, DT, dt_projb, M, DI_, DTR_, XPN_, DTR_, DI_);

    // 6) chunked selective scan (y fp32 into XZ xb half, in place)
    scan_chunk<<<dim3(8, CH_, B_), 256, 0, stream>>>(U, DT, XDBL, A_log, XZ, HEND);
    scan_mid<<<NCH_ / 256, 256, 0, stream>>>(DT, A_log, HEND);
    scan_fix<<<dim3(8, CH_, B_), 256, 0, stream>>>(U, DT, XDBL, A_log, Dp, HEND, XZ);

    // 7) split y and out_proj (U/XDBL/DT regions dead now)
    split_y<<<(M * DI_) / 1024, 256, 0, stream>>>(XZ, YH, YL);
    split_flat<<<NO / 1024, 256, 0, stream>>>(out_proj, OH, OL, NO);

    // 8) out = y @ out_proj^T  (MFMA split-bf16)  [4096 x 1024], K=2048
    gemm_mfma<<<dim3(8, 32), 256, 0, stream>>>(
        YH, YL, DI_, OH, OL, DI_, (float*)d_out, DM_, DI_);
}

// Round 5
// 668.876 us; speedup vs baseline: 7.7000x; 1.9757x over previous
//
#include <hip/hip_runtime.h>
#include <hip/hip_bf16.h>
#include <math.h>

// All reference tensors are jnp.float32.

#define B_ 2
#define L_ 2048
#define DM_ 1024
#define DI_ 2048
#define NS_ 16
#define DTR_ 128
#define XPN_ 160   // DTR + 2*NS
#define CH_ 8      // chunks over L
#define CL_ 256    // L / CH_
#define NCH_ 4096  // B_ * DI_

typedef __attribute__((ext_vector_type(8))) short short8;
typedef __attribute__((ext_vector_type(4))) float f32x4;

__device__ inline unsigned short bfbits(float f) {
    __hip_bfloat16 h = __float2bfloat16(f);
    return *reinterpret_cast<unsigned short*>(&h);
}
__device__ inline float bff(unsigned short u) {
    __hip_bfloat16 h;
    *reinterpret_cast<unsigned short*>(&h) = u;
    return __bfloat162float(h);
}

// ---------------- fp32 -> bf16 hi/lo split (flat) ----------------
__global__ __launch_bounds__(256) void split_flat(
    const float* __restrict__ s, unsigned short* __restrict__ hi,
    unsigned short* __restrict__ lo, int n)
{
    int i = (blockIdx.x * 256 + threadIdx.x) * 4;
    if (i >= n) return;
    float4 v = *(const float4*)(s + i);
    float f[4] = {v.x, v.y, v.z, v.w};
    unsigned short hh[4], ll[4];
#pragma unroll
    for (int c = 0; c < 4; ++c) {
        hh[c] = bfbits(f[c]);
        ll[c] = bfbits(f[c] - bff(hh[c]));
    }
    *(ushort4*)(hi + i) = make_ushort4(hh[0], hh[1], hh[2], hh[3]);
    *(ushort4*)(lo + i) = make_ushort4(ll[0], ll[1], ll[2], ll[3]);
}

// ---------------- strided split: y (cols 0..DI-1 of XZ) ----------------
__global__ __launch_bounds__(256) void split_y(
    const float* __restrict__ XZ, unsigned short* __restrict__ hi,
    unsigned short* __restrict__ lo)
{
    int idx = blockIdx.x * 256 + threadIdx.x;     // over M*DI/4
    int t = idx >> 9;                             // DI_/4 = 512
    int d = (idx & 511) * 4;
    float4 v = *(const float4*)(XZ + (long)t * (2 * DI_) + d);
    float f[4] = {v.x, v.y, v.z, v.w};
    unsigned short hh[4], ll[4];
#pragma unroll
    for (int c = 0; c < 4; ++c) {
        hh[c] = bfbits(f[c]);
        ll[c] = bfbits(f[c] - bff(hh[c]));
    }
    long o = (long)t * DI_ + d;
    *(ushort4*)(hi + o) = make_ushort4(hh[0], hh[1], hh[2], hh[3]);
    *(ushort4*)(lo + o) = make_ushort4(ll[0], ll[1], ll[2], ll[3]);
}

// ---------------- MFMA split-bf16 GEMM (pre-split inputs): C = A @ B^T ----
// 128x128 block, 4 waves, each wave 64x64 = 4x4 tiles of 16x16, KT=32.
// M,N multiples of 128; K multiple of 32.
__global__ __launch_bounds__(256) void gemm_mfma(
    const unsigned short* __restrict__ Ah, const unsigned short* __restrict__ Al, int lda,
    const unsigned short* __restrict__ Bh, const unsigned short* __restrict__ Bl, int ldb,
    float* __restrict__ C, int ldc, int K)
{
    __shared__ unsigned short sA[2][128][40];
    __shared__ unsigned short sB[2][128][40];
    const int tid = threadIdx.x;
    const int lane = tid & 63, wave = tid >> 6;
    const int row0 = blockIdx.y * 128, col0 = blockIdx.x * 128;
    const int wm = (wave & 1) << 6, wn = (wave >> 1) << 6;
    const int m = lane & 15;
    const int ko = (lane >> 4) << 3;

    f32x4 acc[4][4];
    const f32x4 zero = {0.f, 0.f, 0.f, 0.f};
#pragma unroll
    for (int i = 0; i < 4; ++i)
#pragma unroll
        for (int j = 0; j < 4; ++j) acc[i][j] = zero;

    for (int k0 = 0; k0 < K; k0 += 32) {
#pragma unroll
        for (int c = 0; c < 2; ++c) {
            int idx = tid + (c << 8);
            int r = idx >> 2;
            int col8 = (idx & 3) << 3;
            *(short8*)&sA[0][r][col8] = *(const short8*)(Ah + (long)(row0 + r) * lda + k0 + col8);
            *(short8*)&sA[1][r][col8] = *(const short8*)(Al + (long)(row0 + r) * lda + k0 + col8);
            *(short8*)&sB[0][r][col8] = *(const short8*)(Bh + (long)(col0 + r) * ldb + k0 + col8);
            *(short8*)&sB[1][r][col8] = *(const short8*)(Bl + (long)(col0 + r) * ldb + k0 + col8);
        }
        __syncthreads();

        short8 ah[4], al[4];
#pragma unroll
        for (int i = 0; i < 4; ++i) {
            ah[i] = *(const short8*)&sA[0][wm + i * 16 + m][ko];
            al[i] = *(const short8*)&sA[1][wm + i * 16 + m][ko];
        }
#pragma unroll
        for (int j = 0; j < 4; ++j) {
            short8 bh = *(const short8*)&sB[0][wn + j * 16 + m][ko];
            short8 bl = *(const short8*)&sB[1][wn + j * 16 + m][ko];
#pragma unroll
            for (int i = 0; i < 4; ++i) {
                acc[i][j] = __builtin_amdgcn_mfma_f32_16x16x32_bf16(ah[i], bh, acc[i][j], 0, 0, 0);
                acc[i][j] = __builtin_amdgcn_mfma_f32_16x16x32_bf16(al[i], bh, acc[i][j], 0, 0, 0);
                acc[i][j] = __builtin_amdgcn_mfma_f32_16x16x32_bf16(ah[i], bl, acc[i][j], 0, 0, 0);
            }
        }
        __syncthreads();
    }

    const int cr = (lane >> 4) << 2;
#pragma unroll
    for (int i = 0; i < 4; ++i) {
#pragma unroll
        for (int j = 0; j < 4; ++j) {
            int gr = row0 + wm + i * 16 + cr;
            int gc = col0 + wn + j * 16 + m;
#pragma unroll
            for (int r = 0; r < 4; ++r)
                C[(long)(gr + r) * ldc + gc] = acc[i][j][r];
        }
    }
}

// ---------------- MFMA GEMM, fp32 inputs, split on the fly ----------------
// C = A @ B^T (+ split-K via blockIdx.z writing to C + z*partStride).
// A: [M,K] fp32 (lda), B: [N,K] fp32 (ldb). M mult of 128; kslice mult of 32.
// N-guarded (B rows >= N staged as zero; writes masked to gc < N).
enum { ME_PART = 0, ME_SOFTPLUS = 1 };

template <int EPI>
__global__ __launch_bounds__(256) void gemm_mf32(
    const float* __restrict__ A, int lda,
    const float* __restrict__ B, int ldb,
    float* __restrict__ C, int ldc,
    const float* __restrict__ bias,
    int N, int kslice, long partStride)
{
    __shared__ unsigned short sA[2][128][40];
    __shared__ unsigned short sB[2][128][40];
    const int tid = threadIdx.x;
    const int lane = tid & 63, wave = tid >> 6;
    const int row0 = blockIdx.y * 128, col0 = blockIdx.x * 128;
    const int wm = (wave & 1) << 6, wn = (wave >> 1) << 6;
    const int m = lane & 15;
    const int ko = (lane >> 4) << 3;

    const int kbeg = blockIdx.z * kslice;
    const int kend = kbeg + kslice;

    f32x4 acc[4][4];
    const f32x4 zero = {0.f, 0.f, 0.f, 0.f};
#pragma unroll
    for (int i = 0; i < 4; ++i)
#pragma unroll
        for (int j = 0; j < 4; ++j) acc[i][j] = zero;

    for (int k0 = kbeg; k0 < kend; k0 += 32) {
        // stage A: 128x32 fp32 -> hi/lo bf16 in LDS (1024 float4s / 256 thr)
#pragma unroll
        for (int c = 0; c < 4; ++c) {
            int idx = tid + (c << 8);
            int r = idx >> 3;                 // 0..127
            int c4 = (idx & 7) << 2;          // 0,4,..,28
            float4 v = *(const float4*)(A + (long)(row0 + r) * lda + k0 + c4);
            float f[4] = {v.x, v.y, v.z, v.w};
            unsigned short hh[4], ll[4];
#pragma unroll
            for (int q = 0; q < 4; ++q) {
                hh[q] = bfbits(f[q]);
                ll[q] = bfbits(f[q] - bff(hh[q]));
            }
            *(ushort4*)&sA[0][r][c4] = make_ushort4(hh[0], hh[1], hh[2], hh[3]);
            *(ushort4*)&sA[1][r][c4] = make_ushort4(ll[0], ll[1], ll[2], ll[3]);
        }
        // stage B with N-guard
#pragma unroll
        for (int c = 0; c < 4; ++c) {
            int idx = tid + (c << 8);
            int r = idx >> 3;
            int c4 = (idx & 7) << 2;
            int gr = col0 + r;
            float4 v = make_float4(0.f, 0.f, 0.f, 0.f);
            if (gr < N) v = *(const float4*)(B + (long)gr * ldb + k0 + c4);
            float f[4] = {v.x, v.y, v.z, v.w};
            unsigned short hh[4], ll[4];
#pragma unroll
            for (int q = 0; q < 4; ++q) {
                hh[q] = bfbits(f[q]);
                ll[q] = bfbits(f[q] - bff(hh[q]));
            }
            *(ushort4*)&sB[0][r][c4] = make_ushort4(hh[0], hh[1], hh[2], hh[3]);
            *(ushort4*)&sB[1][r][c4] = make_ushort4(ll[0], ll[1], ll[2], ll[3]);
        }
        __syncthreads();

        short8 ah[4], al[4];
#pragma unroll
        for (int i = 0; i < 4; ++i) {
            ah[i] = *(const short8*)&sA[0][wm + i * 16 + m][ko];
            al[i] = *(const short8*)&sA[1][wm + i * 16 + m][ko];
        }
#pragma unroll
        for (int j = 0; j < 4; ++j) {
            short8 bh = *(const short8*)&sB[0][wn + j * 16 + m][ko];
            short8 bl = *(const short8*)&sB[1][wn + j * 16 + m][ko];
#pragma unroll
            for (int i = 0; i < 4; ++i) {
                acc[i][j] = __builtin_amdgcn_mfma_f32_16x16x32_bf16(ah[i], bh, acc[i][j], 0, 0, 0);
                acc[i][j] = __builtin_amdgcn_mfma_f32_16x16x32_bf16(al[i], bh, acc[i][j], 0, 0, 0);
                acc[i][j] = __builtin_amdgcn_mfma_f32_16x16x32_bf16(ah[i], bl, acc[i][j], 0, 0, 0);
            }
        }
        __syncthreads();
    }

    const int cr = (lane >> 4) << 2;
    float* Cp = C + (long)blockIdx.z * partStride;
#pragma unroll
    for (int i = 0; i < 4; ++i) {
#pragma unroll
        for (int j = 0; j < 4; ++j) {
            int gr = row0 + wm + i * 16 + cr;
            int gc = col0 + wn + j * 16 + m;
            if (gc >= N) continue;
#pragma unroll
            for (int r = 0; r < 4; ++r) {
                float v = acc[i][j][r];
                if (EPI == ME_SOFTPLUS) {
                    v += bias[gc];
                    v = (v > 20.f) ? v : log1pf(__expf(v));
                }
                Cp[(long)(gr + r) * ldc + gc] = v;
            }
        }
    }
}

// ---------------- split-K partial reduction: O = sum_s P[s] ----------------
__global__ __launch_bounds__(256) void reduce_part(
    const float* __restrict__ P, float* __restrict__ O, int n)
{
    int i = (blockIdx.x * 256 + threadIdx.x) * 4;
    if (i >= n) return;
    float4 s = *(const float4*)(P + i);
#pragma unroll
    for (int k = 1; k < 8; ++k) {
        float4 v = *(const float4*)(P + (long)k * n + i);
        s.x += v.x; s.y += v.y; s.z += v.z; s.w += v.w;
    }
    *(float4*)(O + i) = s;
}

// ---------------- causal depthwise conv(4) + bias + SiLU ----------------
__global__ __launch_bounds__(256) void conv_silu(
    const float* __restrict__ xz, const float* __restrict__ w,
    const float* __restrict__ bc, float* __restrict__ U)
{
    int idx = blockIdx.x * 256 + threadIdx.x;       // (b*L + t)*DI + d
    if (idx >= B_ * L_ * DI_) return;
    int d = idx & (DI_ - 1);
    int bt = idx >> 11;
    int t = bt & (L_ - 1);
    float s = bc[d];
#pragma unroll
    for (int j = 0; j < 4; ++j) {
        int tt = t - 3 + j;
        if (tt >= 0)
            s += w[d * 4 + j] * xz[((long)(bt - t + tt)) * (2 * DI_) + d];
    }
    U[idx] = s / (1.f + __expf(-s));                // silu
}

// ---------------- Pass A: per-chunk local scan ----------------
__global__ __launch_bounds__(256) void scan_chunk(
    const float* __restrict__ U, float* __restrict__ DT,
    const float* __restrict__ XDBL, const float* __restrict__ A_log,
    float* __restrict__ XZ, float* __restrict__ HEND)
{
    const int d = blockIdx.x * 256 + threadIdx.x;
    const int chunk = blockIdx.y;
    const int b = blockIdx.z;
    const int channel = b * DI_ + d;
    const long t0 = (long)b * L_ + chunk * CL_;

    float An[NS_], h[NS_];
#pragma unroll
    for (int n = 0; n < NS_; ++n) {
        An[n] = -__expf(A_log[d * NS_ + n]);
        h[n] = 0.f;
    }
    float sum_dt = 0.f;
    __shared__ float sB[8][NS_], sC[8][NS_];

    for (int tt0 = 0; tt0 < CL_; tt0 += 8) {
        const long bt0 = t0 + tt0;
        {
            int i = threadIdx.x >> 5, j = threadIdx.x & 31;
            float v = XDBL[(bt0 + i) * XPN_ + DTR_ + j];
            if (j < NS_) sB[i][j] = v; else sC[i][j - NS_] = v;
        }
        __syncthreads();
        float u8[8], dt8[8], y8[8], cum8[8];
#pragma unroll
        for (int i = 0; i < 8; ++i) u8[i] = U[(bt0 + i) * DI_ + d];
#pragma unroll
        for (int i = 0; i < 8; ++i) dt8[i] = DT[(bt0 + i) * DI_ + d];
#pragma unroll
        for (int i = 0; i < 8; ++i) {
            const float dt = dt8[i];
            sum_dt += dt;
            cum8[i] = sum_dt;
            const float du = dt * u8[i];
            float y = 0.f;
#pragma unroll
            for (int n = 0; n < NS_; ++n) {
                h[n] = __expf(An[n] * dt) * h[n] + du * sB[i][n];
                y += h[n] * sC[i][n];
            }
            y8[i] = y;
        }
#pragma unroll
        for (int i = 0; i < 8; ++i) XZ[(bt0 + i) * (2 * DI_) + d] = y8[i];
#pragma unroll
        for (int i = 0; i < 8; ++i) DT[(bt0 + i) * DI_ + d] = cum8[i];
        __syncthreads();
    }
#pragma unroll
    for (int n = 0; n < NS_; ++n)
        HEND[(chunk * NS_ + n) * NCH_ + channel] = h[n];
}

// ---------------- Pass B: combine chunk states (in-place) ----------------
__global__ __launch_bounds__(256) void scan_mid(
    const float* __restrict__ DT, const float* __restrict__ A_log,
    float* __restrict__ HST)
{
    const int channel = blockIdx.x * 256 + threadIdx.x;
    const int b = channel / DI_, d = channel % DI_;
    float An[NS_], h0[NS_];
#pragma unroll
    for (int n = 0; n < NS_; ++n) {
        An[n] = -__expf(A_log[d * NS_ + n]);
        h0[n] = 0.f;
    }
    for (int c = 0; c < CH_; ++c) {
        float he[NS_];
#pragma unroll
        for (int n = 0; n < NS_; ++n) {
            he[n] = HST[(c * NS_ + n) * NCH_ + channel];
            HST[(c * NS_ + n) * NCH_ + channel] = h0[n];
        }
        if (c < CH_ - 1) {
            const float S = DT[((long)b * L_ + c * CL_ + CL_ - 1) * DI_ + d];
#pragma unroll
            for (int n = 0; n < NS_; ++n)
                h0[n] = __expf(An[n] * S) * h0[n] + he[n];
        }
    }
}

// ---------------- Pass C: correction + D-skip + z-gating ----------------
__global__ __launch_bounds__(256) void scan_fix(
    const float* __restrict__ U, const float* __restrict__ DT,
    const float* __restrict__ XDBL, const float* __restrict__ A_log,
    const float* __restrict__ Dp, const float* __restrict__ HST,
    float* __restrict__ XZ)
{
    const int d = blockIdx.x * 256 + threadIdx.x;
    const int chunk = blockIdx.y;
    const int b = blockIdx.z;
    const int channel = b * DI_ + d;
    const long t0 = (long)b * L_ + chunk * CL_;

    float An[NS_], h0[NS_];
#pragma unroll
    for (int n = 0; n < NS_; ++n) {
        An[n] = -__expf(A_log[d * NS_ + n]);
        h0[n] = HST[(chunk * NS_ + n) * NCH_ + channel];
    }
    const float Dd = Dp[d];
    __shared__ float sC[8][NS_];

    for (int tt0 = 0; tt0 < CL_; tt0 += 8) {
        const long bt0 = t0 + tt0;
        if (threadIdx.x < 128) {
            int i = threadIdx.x >> 4, n = threadIdx.x & 15;
            sC[i][n] = XDBL[(bt0 + i) * XPN_ + DTR_ + NS_ + n];
        }
        __syncthreads();
        float cum8[8], yp8[8], u8[8], z8[8];
#pragma unroll
        for (int i = 0; i < 8; ++i) cum8[i] = DT[(bt0 + i) * DI_ + d];
#pragma unroll
        for (int i = 0; i < 8; ++i) yp8[i] = XZ[(bt0 + i) * (2 * DI_) + d];
#pragma unroll
        for (int i = 0; i < 8; ++i) u8[i] = U[(bt0 + i) * DI_ + d];
#pragma unroll
        for (int i = 0; i < 8; ++i) z8[i] = XZ[(bt0 + i) * (2 * DI_) + DI_ + d];
#pragma unroll
        for (int i = 0; i < 8; ++i) {
            float corr = 0.f;
#pragma unroll
            for (int n = 0; n < NS_; ++n)
                corr += sC[i][n] * __expf(An[n] * cum8[i]) * h0[n];
            const float y = yp8[i] + corr + u8[i] * Dd;
            const float z = z8[i];
            yp8[i] = y * (z / (1.f + __expf(-z)));
        }
#pragma unroll
        for (int i = 0; i < 8; ++i) XZ[(bt0 + i) * (2 * DI_) + d] = yp8[i];
        __syncthreads();
    }
}

extern "C" void kernel_launch(void* const* d_in, const int* in_sizes, int n_in,
                              void* d_out, int out_size, void* d_ws, size_t ws_size,
                              hipStream_t stream)
{
    const float* x        = (const float*)d_in[0];
    const float* in_proj  = (const float*)d_in[1];
    const float* conv_w   = (const float*)d_in[2];
    const float* conv_b   = (const float*)d_in[3];
    const float* x_proj   = (const float*)d_in[4];
    const float* dt_proj  = (const float*)d_in[5];
    const float* dt_projb = (const float*)d_in[6];
    const float* A_log    = (const float*)d_in[7];
    const float* Dp       = (const float*)d_in[8];
    const float* out_proj = (const float*)d_in[9];

    const int M = B_ * L_;                       // 4096
    float* XZ   = (float*)d_ws;                  // [M, 2*DI]   67 MB
    float* U    = XZ + (size_t)M * 2 * DI_;      // [M, DI]     33.5 MB
    float* XDBL = U + (size_t)M * DI_;           // [M, 160]    2.6 MB
    float* DT   = XDBL + (size_t)M * XPN_;       // [M, DI]     33.5 MB
    float* HEND = DT + (size_t)M * DI_;          // 2 MB

    // --- overlays (disjoint lifetimes) ---
    const int NX = M * DM_;
    const int NO = DM_ * DI_;
    unsigned short* XH = (unsigned short*)U;          // dead before conv writes U
    unsigned short* XL = XH + NX;
    unsigned short* WH = (unsigned short*)DT;         // dead after GEMM1
    unsigned short* WL = WH + NX;
    float* PART = DT;                                 // [8][M][160] = 21 MB, dead after reduce
    unsigned short* YH = (unsigned short*)U;          // U dead after scan_fix
    unsigned short* YL = YH + (size_t)M * DI_;
    unsigned short* OH = (unsigned short*)DT;         // DT dead after scan_fix
    unsigned short* OL = OH + NO;

    // 1) split x and in_proj to bf16 hi/lo
    split_flat<<<NX / 1024, 256, 0, stream>>>(x, XH, XL, NX);
    split_flat<<<NX / 1024, 256, 0, stream>>>(in_proj, WH, WL, NX);

    // 2) xz = x @ in_proj^T  (MFMA split-bf16)  [4096 x 4096], K=1024
    gemm_mfma<<<dim3(32, 32), 256, 0, stream>>>(
        XH, XL, DM_, WH, WL, DM_, XZ, 2 * DI_, DM_);

    // 3) u = silu(conv(xb) + b)
    conv_silu<<<(M * DI_ + 255) / 256, 256, 0, stream>>>(XZ, conv_w, conv_b, U);

    // 4) x_dbl = u @ x_proj^T   [4096 x 160], K=2048; split-K x8 -> PART, reduce
    gemm_mf32<ME_PART><<<dim3(2, 32, 8), 256, 0, stream>>>(
        U, DI_, x_proj, DI_, PART, XPN_, nullptr, XPN_, 256, (long)M * XPN_);
    reduce_part<<<(M * XPN_) / 1024, 256, 0, stream>>>(PART, XDBL, M * XPN_);

    // 5) dt = softplus(x_dbl[:, :128] @ dt_proj^T + b)   [4096 x 2048], K=128
    gemm_mf32<ME_SOFTPLUS><<<dim3(16, 32, 1), 256, 0, stream>>>(
        XDBL, XPN_, dt_proj, DTR_, DT, DI_, dt_projb, DI_, DTR_, 0);

    // 6) chunked selective scan (y fp32 into XZ xb half)
    scan_chunk<<<dim3(8, CH_, B_), 256, 0, stream>>>(U, DT, XDBL, A_log, XZ, HEND);
    scan_mid<<<NCH_ / 256, 256, 0, stream>>>(DT, A_log, HEND);
    scan_fix<<<dim3(8, CH_, B_), 256, 0, stream>>>(U, DT, XDBL, A_log, Dp, HEND, XZ);

    // 7) split y and out_proj
    split_y<<<(M * DI_) / 1024, 256, 0, stream>>>(XZ, YH, YL);
    split_flat<<<NO / 1024, 256, 0, stream>>>(out_proj, OH, OL, NO);

    // 8) out = y @ out_proj^T  (MFMA split-bf16)  [4096 x 1024], K=2048
    gemm_mfma<<<dim3(8, 32), 256, 0, stream>>>(
        YH, YL, DI_, OH, OL, DI_, (float*)d_out, DM_, DI_);
}

// Round 6
// 563.816 us; speedup vs baseline: 9.1348x; 1.1863x over previous
//
#include <hip/hip_runtime.h>
#include <hip/hip_bf16.h>
#include <math.h>

// All reference tensors are jnp.float32.

#define B_ 2
#define L_ 2048
#define DM_ 1024
#define DI_ 2048
#define NS_ 16
#define DTR_ 128
#define XPN_ 160   // DTR + 2*NS
#define CH_ 32     // chunks over L
#define CL_ 64     // L / CH_
#define NCH_ 4096  // B_ * DI_

typedef __attribute__((ext_vector_type(8))) short short8;
typedef __attribute__((ext_vector_type(4))) float f32x4;

__device__ inline unsigned short bfbits(float f) {
    __hip_bfloat16 h = __float2bfloat16(f);
    return *reinterpret_cast<unsigned short*>(&h);
}
__device__ inline float bff(unsigned short u) {
    __hip_bfloat16 h;
    *reinterpret_cast<unsigned short*>(&h) = u;
    return __bfloat162float(h);
}

// ---------------- fp32 -> bf16 hi/lo split (flat) ----------------
__global__ __launch_bounds__(256) void split_flat(
    const float* __restrict__ s, unsigned short* __restrict__ hi,
    unsigned short* __restrict__ lo, int n)
{
    int i = (blockIdx.x * 256 + threadIdx.x) * 4;
    if (i >= n) return;
    float4 v = *(const float4*)(s + i);
    float f[4] = {v.x, v.y, v.z, v.w};
    unsigned short hh[4], ll[4];
#pragma unroll
    for (int c = 0; c < 4; ++c) {
        hh[c] = bfbits(f[c]);
        ll[c] = bfbits(f[c] - bff(hh[c]));
    }
    *(ushort4*)(hi + i) = make_ushort4(hh[0], hh[1], hh[2], hh[3]);
    *(ushort4*)(lo + i) = make_ushort4(ll[0], ll[1], ll[2], ll[3]);
}

// ---------------- strided split: y (cols 0..DI-1 of XZ) ----------------
__global__ __launch_bounds__(256) void split_y(
    const float* __restrict__ XZ, unsigned short* __restrict__ hi,
    unsigned short* __restrict__ lo)
{
    int idx = blockIdx.x * 256 + threadIdx.x;     // over M*DI/4
    int t = idx >> 9;                             // DI_/4 = 512
    int d = (idx & 511) * 4;
    float4 v = *(const float4*)(XZ + (long)t * (2 * DI_) + d);
    float f[4] = {v.x, v.y, v.z, v.w};
    unsigned short hh[4], ll[4];
#pragma unroll
    for (int c = 0; c < 4; ++c) {
        hh[c] = bfbits(f[c]);
        ll[c] = bfbits(f[c] - bff(hh[c]));
    }
    long o = (long)t * DI_ + d;
    *(ushort4*)(hi + o) = make_ushort4(hh[0], hh[1], hh[2], hh[3]);
    *(ushort4*)(lo + o) = make_ushort4(ll[0], ll[1], ll[2], ll[3]);
}

// ---------------- MFMA split-bf16 GEMM (pre-split inputs): C = A @ B^T ----
// 128x128 block, 4 waves, each wave 64x64 = 4x4 tiles of 16x16, KT=32.
__global__ __launch_bounds__(256) void gemm_mfma(
    const unsigned short* __restrict__ Ah, const unsigned short* __restrict__ Al, int lda,
    const unsigned short* __restrict__ Bh, const unsigned short* __restrict__ Bl, int ldb,
    float* __restrict__ C, int ldc, int K)
{
    __shared__ unsigned short sA[2][128][40];
    __shared__ unsigned short sB[2][128][40];
    const int tid = threadIdx.x;
    const int lane = tid & 63, wave = tid >> 6;
    const int row0 = blockIdx.y * 128, col0 = blockIdx.x * 128;
    const int wm = (wave & 1) << 6, wn = (wave >> 1) << 6;
    const int m = lane & 15;
    const int ko = (lane >> 4) << 3;

    f32x4 acc[4][4];
    const f32x4 zero = {0.f, 0.f, 0.f, 0.f};
#pragma unroll
    for (int i = 0; i < 4; ++i)
#pragma unroll
        for (int j = 0; j < 4; ++j) acc[i][j] = zero;

    for (int k0 = 0; k0 < K; k0 += 32) {
#pragma unroll
        for (int c = 0; c < 2; ++c) {
            int idx = tid + (c << 8);
            int r = idx >> 2;
            int col8 = (idx & 3) << 3;
            *(short8*)&sA[0][r][col8] = *(const short8*)(Ah + (long)(row0 + r) * lda + k0 + col8);
            *(short8*)&sA[1][r][col8] = *(const short8*)(Al + (long)(row0 + r) * lda + k0 + col8);
            *(short8*)&sB[0][r][col8] = *(const short8*)(Bh + (long)(col0 + r) * ldb + k0 + col8);
            *(short8*)&sB[1][r][col8] = *(const short8*)(Bl + (long)(col0 + r) * ldb + k0 + col8);
        }
        __syncthreads();

        short8 ah[4], al[4];
#pragma unroll
        for (int i = 0; i < 4; ++i) {
            ah[i] = *(const short8*)&sA[0][wm + i * 16 + m][ko];
            al[i] = *(const short8*)&sA[1][wm + i * 16 + m][ko];
        }
#pragma unroll
        for (int j = 0; j < 4; ++j) {
            short8 bh = *(const short8*)&sB[0][wn + j * 16 + m][ko];
            short8 bl = *(const short8*)&sB[1][wn + j * 16 + m][ko];
#pragma unroll
            for (int i = 0; i < 4; ++i) {
                acc[i][j] = __builtin_amdgcn_mfma_f32_16x16x32_bf16(ah[i], bh, acc[i][j], 0, 0, 0);
                acc[i][j] = __builtin_amdgcn_mfma_f32_16x16x32_bf16(al[i], bh, acc[i][j], 0, 0, 0);
                acc[i][j] = __builtin_amdgcn_mfma_f32_16x16x32_bf16(ah[i], bl, acc[i][j], 0, 0, 0);
            }
        }
        __syncthreads();
    }

    const int cr = (lane >> 4) << 2;
#pragma unroll
    for (int i = 0; i < 4; ++i) {
#pragma unroll
        for (int j = 0; j < 4; ++j) {
            int gr = row0 + wm + i * 16 + cr;
            int gc = col0 + wn + j * 16 + m;
#pragma unroll
            for (int r = 0; r < 4; ++r)
                C[(long)(gr + r) * ldc + gc] = acc[i][j][r];
        }
    }
}

// ---------------- MFMA GEMM, fp32 inputs, split on the fly ----------------
enum { ME_PART = 0, ME_SOFTPLUS = 1 };

template <int EPI>
__global__ __launch_bounds__(256) void gemm_mf32(
    const float* __restrict__ A, int lda,
    const float* __restrict__ B, int ldb,
    float* __restrict__ C, int ldc,
    const float* __restrict__ bias,
    int N, int kslice, long partStride)
{
    __shared__ unsigned short sA[2][128][40];
    __shared__ unsigned short sB[2][128][40];
    const int tid = threadIdx.x;
    const int lane = tid & 63, wave = tid >> 6;
    const int row0 = blockIdx.y * 128, col0 = blockIdx.x * 128;
    const int wm = (wave & 1) << 6, wn = (wave >> 1) << 6;
    const int m = lane & 15;
    const int ko = (lane >> 4) << 3;

    const int kbeg = blockIdx.z * kslice;
    const int kend = kbeg + kslice;

    f32x4 acc[4][4];
    const f32x4 zero = {0.f, 0.f, 0.f, 0.f};
#pragma unroll
    for (int i = 0; i < 4; ++i)
#pragma unroll
        for (int j = 0; j < 4; ++j) acc[i][j] = zero;

    for (int k0 = kbeg; k0 < kend; k0 += 32) {
#pragma unroll
        for (int c = 0; c < 4; ++c) {
            int idx = tid + (c << 8);
            int r = idx >> 3;
            int c4 = (idx & 7) << 2;
            float4 v = *(const float4*)(A + (long)(row0 + r) * lda + k0 + c4);
            float f[4] = {v.x, v.y, v.z, v.w};
            unsigned short hh[4], ll[4];
#pragma unroll
            for (int q = 0; q < 4; ++q) {
                hh[q] = bfbits(f[q]);
                ll[q] = bfbits(f[q] - bff(hh[q]));
            }
            *(ushort4*)&sA[0][r][c4] = make_ushort4(hh[0], hh[1], hh[2], hh[3]);
            *(ushort4*)&sA[1][r][c4] = make_ushort4(ll[0], ll[1], ll[2], ll[3]);
        }
#pragma unroll
        for (int c = 0; c < 4; ++c) {
            int idx = tid + (c << 8);
            int r = idx >> 3;
            int c4 = (idx & 7) << 2;
            int gr = col0 + r;
            float4 v = make_float4(0.f, 0.f, 0.f, 0.f);
            if (gr < N) v = *(const float4*)(B + (long)gr * ldb + k0 + c4);
            float f[4] = {v.x, v.y, v.z, v.w};
            unsigned short hh[4], ll[4];
#pragma unroll
            for (int q = 0; q < 4; ++q) {
                hh[q] = bfbits(f[q]);
                ll[q] = bfbits(f[q] - bff(hh[q]));
            }
            *(ushort4*)&sB[0][r][c4] = make_ushort4(hh[0], hh[1], hh[2], hh[3]);
            *(ushort4*)&sB[1][r][c4] = make_ushort4(ll[0], ll[1], ll[2], ll[3]);
        }
        __syncthreads();

        short8 ah[4], al[4];
#pragma unroll
        for (int i = 0; i < 4; ++i) {
            ah[i] = *(const short8*)&sA[0][wm + i * 16 + m][ko];
            al[i] = *(const short8*)&sA[1][wm + i * 16 + m][ko];
        }
#pragma unroll
        for (int j = 0; j < 4; ++j) {
            short8 bh = *(const short8*)&sB[0][wn + j * 16 + m][ko];
            short8 bl = *(const short8*)&sB[1][wn + j * 16 + m][ko];
#pragma unroll
            for (int i = 0; i < 4; ++i) {
                acc[i][j] = __builtin_amdgcn_mfma_f32_16x16x32_bf16(ah[i], bh, acc[i][j], 0, 0, 0);
                acc[i][j] = __builtin_amdgcn_mfma_f32_16x16x32_bf16(al[i], bh, acc[i][j], 0, 0, 0);
                acc[i][j] = __builtin_amdgcn_mfma_f32_16x16x32_bf16(ah[i], bl, acc[i][j], 0, 0, 0);
            }
        }
        __syncthreads();
    }

    const int cr = (lane >> 4) << 2;
    float* Cp = C + (long)blockIdx.z * partStride;
#pragma unroll
    for (int i = 0; i < 4; ++i) {
#pragma unroll
        for (int j = 0; j < 4; ++j) {
            int gr = row0 + wm + i * 16 + cr;
            int gc = col0 + wn + j * 16 + m;
            if (gc >= N) continue;
#pragma unroll
            for (int r = 0; r < 4; ++r) {
                float v = acc[i][j][r];
                if (EPI == ME_SOFTPLUS) {
                    v += bias[gc];
                    v = (v > 20.f) ? v : log1pf(__expf(v));
                }
                Cp[(long)(gr + r) * ldc + gc] = v;
            }
        }
    }
}

// ---------------- split-K partial reduction: O = sum_s P[s] ----------------
__global__ __launch_bounds__(256) void reduce_part(
    const float* __restrict__ P, float* __restrict__ O, int n)
{
    int i = (blockIdx.x * 256 + threadIdx.x) * 4;
    if (i >= n) return;
    float4 s = *(const float4*)(P + i);
#pragma unroll
    for (int k = 1; k < 8; ++k) {
        float4 v = *(const float4*)(P + (long)k * n + i);
        s.x += v.x; s.y += v.y; s.z += v.z; s.w += v.w;
    }
    *(float4*)(O + i) = s;
}

// ---------------- causal depthwise conv(4) + bias + SiLU ----------------
__global__ __launch_bounds__(256) void conv_silu(
    const float* __restrict__ xz, const float* __restrict__ w,
    const float* __restrict__ bc, float* __restrict__ U)
{
    int idx = blockIdx.x * 256 + threadIdx.x;       // (b*L + t)*DI + d
    if (idx >= B_ * L_ * DI_) return;
    int d = idx & (DI_ - 1);
    int bt = idx >> 11;
    int t = bt & (L_ - 1);
    float s = bc[d];
#pragma unroll
    for (int j = 0; j < 4; ++j) {
        int tt = t - 3 + j;
        if (tt >= 0)
            s += w[d * 4 + j] * xz[((long)(bt - t + tt)) * (2 * DI_) + d];
    }
    U[idx] = s / (1.f + __expf(-s));                // silu
}

// ---------------- Pass A: per-chunk local scan (CL_=64 steps) ----------------
__global__ __launch_bounds__(256) void scan_chunk(
    const float* __restrict__ U, float* __restrict__ DT,
    const float* __restrict__ XDBL, const float* __restrict__ A_log,
    float* __restrict__ XZ, float* __restrict__ HEND)
{
    const int d = blockIdx.x * 256 + threadIdx.x;
    const int chunk = blockIdx.y;
    const int b = blockIdx.z;
    const int channel = b * DI_ + d;
    const long t0 = (long)b * L_ + chunk * CL_;

    float An[NS_], h[NS_];
#pragma unroll
    for (int n = 0; n < NS_; ++n) {
        An[n] = -__expf(A_log[d * NS_ + n]);
        h[n] = 0.f;
    }
    float sum_dt = 0.f;
    __shared__ float sB[8][NS_], sC[8][NS_];

    for (int tt0 = 0; tt0 < CL_; tt0 += 8) {
        const long bt0 = t0 + tt0;
        {
            int i = threadIdx.x >> 5, j = threadIdx.x & 31;
            float v = XDBL[(bt0 + i) * XPN_ + DTR_ + j];
            if (j < NS_) sB[i][j] = v; else sC[i][j - NS_] = v;
        }
        __syncthreads();
        float u8[8], dt8[8], y8[8], cum8[8];
#pragma unroll
        for (int i = 0; i < 8; ++i) u8[i] = U[(bt0 + i) * DI_ + d];
#pragma unroll
        for (int i = 0; i < 8; ++i) dt8[i] = DT[(bt0 + i) * DI_ + d];
#pragma unroll
        for (int i = 0; i < 8; ++i) {
            const float dt = dt8[i];
            sum_dt += dt;
            cum8[i] = sum_dt;
            const float du = dt * u8[i];
            float y = 0.f;
#pragma unroll
            for (int n = 0; n < NS_; ++n) {
                h[n] = __expf(An[n] * dt) * h[n] + du * sB[i][n];
                y += h[n] * sC[i][n];
            }
            y8[i] = y;
        }
#pragma unroll
        for (int i = 0; i < 8; ++i) XZ[(bt0 + i) * (2 * DI_) + d] = y8[i];
#pragma unroll
        for (int i = 0; i < 8; ++i) DT[(bt0 + i) * DI_ + d] = cum8[i];
        __syncthreads();
    }
#pragma unroll
    for (int n = 0; n < NS_; ++n)
        HEND[(chunk * NS_ + n) * NCH_ + channel] = h[n];
}

// ---------------- Pass B: combine chunk states (in-place) ----------------
__global__ __launch_bounds__(256) void scan_mid(
    const float* __restrict__ DT, const float* __restrict__ A_log,
    float* __restrict__ HST)
{
    const int channel = blockIdx.x * 256 + threadIdx.x;
    const int b = channel / DI_, d = channel % DI_;
    float An[NS_], h0[NS_];
#pragma unroll
    for (int n = 0; n < NS_; ++n) {
        An[n] = -__expf(A_log[d * NS_ + n]);
        h0[n] = 0.f;
    }
    for (int c = 0; c < CH_; ++c) {
        float he[NS_];
#pragma unroll
        for (int n = 0; n < NS_; ++n) {
            he[n] = HST[(c * NS_ + n) * NCH_ + channel];
            HST[(c * NS_ + n) * NCH_ + channel] = h0[n];
        }
        if (c < CH_ - 1) {
            const float S = DT[((long)b * L_ + c * CL_ + CL_ - 1) * DI_ + d];
#pragma unroll
            for (int n = 0; n < NS_; ++n)
                h0[n] = __expf(An[n] * S) * h0[n] + he[n];
        }
    }
}

// ---------------- Pass C: correction + D-skip + z-gating ----------------
__global__ __launch_bounds__(256) void scan_fix(
    const float* __restrict__ U, const float* __restrict__ DT,
    const float* __restrict__ XDBL, const float* __restrict__ A_log,
    const float* __restrict__ Dp, const float* __restrict__ HST,
    float* __restrict__ XZ)
{
    const int d = blockIdx.x * 256 + threadIdx.x;
    const int chunk = blockIdx.y;
    const int b = blockIdx.z;
    const int channel = b * DI_ + d;
    const long t0 = (long)b * L_ + chunk * CL_;

    float An[NS_], h0[NS_];
#pragma unroll
    for (int n = 0; n < NS_; ++n) {
        An[n] = -__expf(A_log[d * NS_ + n]);
        h0[n] = HST[(chunk * NS_ + n) * NCH_ + channel];
    }
    const float Dd = Dp[d];
    __shared__ float sC[8][NS_];

    for (int tt0 = 0; tt0 < CL_; tt0 += 8) {
        const long bt0 = t0 + tt0;
        if (threadIdx.x < 128) {
            int i = threadIdx.x >> 4, n = threadIdx.x & 15;
            sC[i][n] = XDBL[(bt0 + i) * XPN_ + DTR_ + NS_ + n];
        }
        __syncthreads();
        float cum8[8], yp8[8], u8[8], z8[8];
#pragma unroll
        for (int i = 0; i < 8; ++i) cum8[i] = DT[(bt0 + i) * DI_ + d];
#pragma unroll
        for (int i = 0; i < 8; ++i) yp8[i] = XZ[(bt0 + i) * (2 * DI_) + d];
#pragma unroll
        for (int i = 0; i < 8; ++i) u8[i] = U[(bt0 + i) * DI_ + d];
#pragma unroll
        for (int i = 0; i < 8; ++i) z8[i] = XZ[(bt0 + i) * (2 * DI_) + DI_ + d];
#pragma unroll
        for (int i = 0; i < 8; ++i) {
            float corr = 0.f;
#pragma unroll
            for (int n = 0; n < NS_; ++n)
                corr += sC[i][n] * __expf(An[n] * cum8[i]) * h0[n];
            const float y = yp8[i] + corr + u8[i] * Dd;
            const float z = z8[i];
            yp8[i] = y * (z / (1.f + __expf(-z)));
        }
#pragma unroll
        for (int i = 0; i < 8; ++i) XZ[(bt0 + i) * (2 * DI_) + d] = yp8[i];
        __syncthreads();
    }
}

extern "C" void kernel_launch(void* const* d_in, const int* in_sizes, int n_in,
                              void* d_out, int out_size, void* d_ws, size_t ws_size,
                              hipStream_t stream)
{
    const float* x        = (const float*)d_in[0];
    const float* in_proj  = (const float*)d_in[1];
    const float* conv_w   = (const float*)d_in[2];
    const float* conv_b   = (const float*)d_in[3];
    const float* x_proj   = (const float*)d_in[4];
    const float* dt_proj  = (const float*)d_in[5];
    const float* dt_projb = (const float*)d_in[6];
    const float* A_log    = (const float*)d_in[7];
    const float* Dp       = (const float*)d_in[8];
    const float* out_proj = (const float*)d_in[9];

    const int M = B_ * L_;                       // 4096
    float* XZ   = (float*)d_ws;                  // [M, 2*DI]   67 MB
    float* U    = XZ + (size_t)M * 2 * DI_;      // [M, DI]     33.5 MB
    float* XDBL = U + (size_t)M * DI_;           // [M, 160]    2.6 MB
    float* DT   = XDBL + (size_t)M * XPN_;       // [M, DI]     33.5 MB
    // HEND/HST ([CH][NS][NCH] = 8.4 MB) lives in d_out (16.8 MB, dead until
    // GEMM4, which overwrites every element).
    float* HEND = (float*)d_out;

    // --- overlays (disjoint lifetimes) ---
    const int NX = M * DM_;
    const int NO = DM_ * DI_;
    unsigned short* XH = (unsigned short*)U;          // dead before conv writes U
    unsigned short* XL = XH + NX;
    unsigned short* WH = (unsigned short*)DT;         // dead after GEMM1
    unsigned short* WL = WH + NX;
    float* PART = DT;                                 // [8][M][160] = 21 MB, dead after reduce
    unsigned short* YH = (unsigned short*)U;          // U dead after scan_fix
    unsigned short* YL = YH + (size_t)M * DI_;
    unsigned short* OH = (unsigned short*)DT;         // DT dead after scan_fix
    unsigned short* OL = OH + NO;

    // 1) split x and in_proj to bf16 hi/lo
    split_flat<<<NX / 1024, 256, 0, stream>>>(x, XH, XL, NX);
    split_flat<<<NX / 1024, 256, 0, stream>>>(in_proj, WH, WL, NX);

    // 2) xz = x @ in_proj^T  (MFMA split-bf16)  [4096 x 4096], K=1024
    gemm_mfma<<<dim3(32, 32), 256, 0, stream>>>(
        XH, XL, DM_, WH, WL, DM_, XZ, 2 * DI_, DM_);

    // 3) u = silu(conv(xb) + b)
    conv_silu<<<(M * DI_ + 255) / 256, 256, 0, stream>>>(XZ, conv_w, conv_b, U);

    // 4) x_dbl = u @ x_proj^T   [4096 x 160], K=2048; split-K x8 -> PART, reduce
    gemm_mf32<ME_PART><<<dim3(2, 32, 8), 256, 0, stream>>>(
        U, DI_, x_proj, DI_, PART, XPN_, nullptr, XPN_, 256, (long)M * XPN_);
    reduce_part<<<(M * XPN_) / 1024, 256, 0, stream>>>(PART, XDBL, M * XPN_);

    // 5) dt = softplus(x_dbl[:, :128] @ dt_proj^T + b)   [4096 x 2048], K=128
    gemm_mf32<ME_SOFTPLUS><<<dim3(16, 32, 1), 256, 0, stream>>>(
        XDBL, XPN_, dt_proj, DTR_, DT, DI_, dt_projb, DI_, DTR_, 0);

    // 6) chunked selective scan (32 chunks of 64; h-state buffer in d_out)
    scan_chunk<<<dim3(8, CH_, B_), 256, 0, stream>>>(U, DT, XDBL, A_log, XZ, HEND);
    scan_mid<<<NCH_ / 256, 256, 0, stream>>>(DT, A_log, HEND);
    scan_fix<<<dim3(8, CH_, B_), 256, 0, stream>>>(U, DT, XDBL, A_log, Dp, HEND, XZ);

    // 7) split y and out_proj
    split_y<<<(M * DI_) / 1024, 256, 0, stream>>>(XZ, YH, YL);
    split_flat<<<NO / 1024, 256, 0, stream>>>(out_proj, OH, OL, NO);

    // 8) out = y @ out_proj^T  (MFMA split-bf16)  [4096 x 1024], K=2048
    gemm_mfma<<<dim3(8, 32), 256, 0, stream>>>(
        YH, YL, DI_, OH, OL, DI_, (float*)d_out, DM_, DI_);
}

// Round 7
// 528.873 us; speedup vs baseline: 9.7383x; 1.0661x over previous
//
#include <hip/hip_runtime.h>
#include <hip/hip_bf16.h>
#include <math.h>

// All reference tensors are jnp.float32. GEMMs run in pure bf16 (fp32 acc).

#define B_ 2
#define L_ 2048
#define DM_ 1024
#define DI_ 2048
#define NS_ 16
#define DTR_ 128
#define XPN_ 160   // DTR + 2*NS
#define CH_ 32     // chunks over L
#define CL_ 64     // L / CH_
#define NCH_ 4096  // B_ * DI_

typedef __attribute__((ext_vector_type(8))) short short8;
typedef __attribute__((ext_vector_type(4))) float f32x4;

__device__ inline unsigned short bfbits(float f) {
    __hip_bfloat16 h = __float2bfloat16(f);
    return *reinterpret_cast<unsigned short*>(&h);
}

// ---------------- fp32 -> bf16 cast (flat) ----------------
__global__ __launch_bounds__(256) void cast_flat(
    const float* __restrict__ s, unsigned short* __restrict__ o, int n)
{
    int i = (blockIdx.x * 256 + threadIdx.x) * 4;
    if (i >= n) return;
    float4 v = *(const float4*)(s + i);
    *(ushort4*)(o + i) = make_ushort4(bfbits(v.x), bfbits(v.y), bfbits(v.z), bfbits(v.w));
}

// ---------------- strided cast: y (cols 0..DI-1 of XZ) ----------------
__global__ __launch_bounds__(256) void cast_y(
    const float* __restrict__ XZ, unsigned short* __restrict__ o)
{
    int idx = blockIdx.x * 256 + threadIdx.x;     // over M*DI/4
    int t = idx >> 9;                             // DI_/4 = 512
    int d = (idx & 511) * 4;
    float4 v = *(const float4*)(XZ + (long)t * (2 * DI_) + d);
    long off = (long)t * DI_ + d;
    *(ushort4*)(o + off) = make_ushort4(bfbits(v.x), bfbits(v.y), bfbits(v.z), bfbits(v.w));
}

// ---------------- MFMA bf16 GEMM (pre-cast inputs): C = A @ B^T ----------
// 128x128 block, 4 waves, each wave 64x64 = 4x4 tiles of 16x16, KT=32.
__global__ __launch_bounds__(256) void gemm_mfma(
    const unsigned short* __restrict__ A, int lda,
    const unsigned short* __restrict__ B, int ldb,
    float* __restrict__ C, int ldc, int K)
{
    __shared__ unsigned short sA[128][40];   // pad 32->40
    __shared__ unsigned short sB[128][40];
    const int tid = threadIdx.x;
    const int lane = tid & 63, wave = tid >> 6;
    const int row0 = blockIdx.y * 128, col0 = blockIdx.x * 128;
    const int wm = (wave & 1) << 6, wn = (wave >> 1) << 6;
    const int m = lane & 15;
    const int ko = (lane >> 4) << 3;

    f32x4 acc[4][4];
    const f32x4 zero = {0.f, 0.f, 0.f, 0.f};
#pragma unroll
    for (int i = 0; i < 4; ++i)
#pragma unroll
        for (int j = 0; j < 4; ++j) acc[i][j] = zero;

    for (int k0 = 0; k0 < K; k0 += 32) {
#pragma unroll
        for (int c = 0; c < 2; ++c) {
            int idx = tid + (c << 8);          // 0..511
            int r = idx >> 2;                  // 0..127
            int col8 = (idx & 3) << 3;         // 0,8,16,24
            *(short8*)&sA[r][col8] = *(const short8*)(A + (long)(row0 + r) * lda + k0 + col8);
            *(short8*)&sB[r][col8] = *(const short8*)(B + (long)(col0 + r) * ldb + k0 + col8);
        }
        __syncthreads();

        short8 af[4];
#pragma unroll
        for (int i = 0; i < 4; ++i)
            af[i] = *(const short8*)&sA[wm + i * 16 + m][ko];
#pragma unroll
        for (int j = 0; j < 4; ++j) {
            short8 bf = *(const short8*)&sB[wn + j * 16 + m][ko];
#pragma unroll
            for (int i = 0; i < 4; ++i)
                acc[i][j] = __builtin_amdgcn_mfma_f32_16x16x32_bf16(af[i], bf, acc[i][j], 0, 0, 0);
        }
        __syncthreads();
    }

    const int cr = (lane >> 4) << 2;
#pragma unroll
    for (int i = 0; i < 4; ++i) {
#pragma unroll
        for (int j = 0; j < 4; ++j) {
            int gr = row0 + wm + i * 16 + cr;
            int gc = col0 + wn + j * 16 + m;
#pragma unroll
            for (int r = 0; r < 4; ++r)
                C[(long)(gr + r) * ldc + gc] = acc[i][j][r];
        }
    }
}

// ---------------- MFMA GEMM, fp32 inputs, cast on the fly ----------------
enum { ME_PART = 0, ME_SOFTPLUS = 1 };

template <int EPI>
__global__ __launch_bounds__(256) void gemm_mf32(
    const float* __restrict__ A, int lda,
    const float* __restrict__ B, int ldb,
    float* __restrict__ C, int ldc,
    const float* __restrict__ bias,
    int N, int kslice, long partStride)
{
    __shared__ unsigned short sA[128][40];
    __shared__ unsigned short sB[128][40];
    const int tid = threadIdx.x;
    const int lane = tid & 63, wave = tid >> 6;
    const int row0 = blockIdx.y * 128, col0 = blockIdx.x * 128;
    const int wm = (wave & 1) << 6, wn = (wave >> 1) << 6;
    const int m = lane & 15;
    const int ko = (lane >> 4) << 3;

    const int kbeg = blockIdx.z * kslice;
    const int kend = kbeg + kslice;

    f32x4 acc[4][4];
    const f32x4 zero = {0.f, 0.f, 0.f, 0.f};
#pragma unroll
    for (int i = 0; i < 4; ++i)
#pragma unroll
        for (int j = 0; j < 4; ++j) acc[i][j] = zero;

    for (int k0 = kbeg; k0 < kend; k0 += 32) {
#pragma unroll
        for (int c = 0; c < 4; ++c) {
            int idx = tid + (c << 8);
            int r = idx >> 3;                 // 0..127
            int c4 = (idx & 7) << 2;          // 0,4,..,28
            float4 v = *(const float4*)(A + (long)(row0 + r) * lda + k0 + c4);
            *(ushort4*)&sA[r][c4] = make_ushort4(bfbits(v.x), bfbits(v.y), bfbits(v.z), bfbits(v.w));
        }
#pragma unroll
        for (int c = 0; c < 4; ++c) {
            int idx = tid + (c << 8);
            int r = idx >> 3;
            int c4 = (idx & 7) << 2;
            int gr = col0 + r;
            float4 v = make_float4(0.f, 0.f, 0.f, 0.f);
            if (gr < N) v = *(const float4*)(B + (long)gr * ldb + k0 + c4);
            *(ushort4*)&sB[r][c4] = make_ushort4(bfbits(v.x), bfbits(v.y), bfbits(v.z), bfbits(v.w));
        }
        __syncthreads();

        short8 af[4];
#pragma unroll
        for (int i = 0; i < 4; ++i)
            af[i] = *(const short8*)&sA[wm + i * 16 + m][ko];
#pragma unroll
        for (int j = 0; j < 4; ++j) {
            short8 bf = *(const short8*)&sB[wn + j * 16 + m][ko];
#pragma unroll
            for (int i = 0; i < 4; ++i)
                acc[i][j] = __builtin_amdgcn_mfma_f32_16x16x32_bf16(af[i], bf, acc[i][j], 0, 0, 0);
        }
        __syncthreads();
    }

    const int cr = (lane >> 4) << 2;
    float* Cp = C + (long)blockIdx.z * partStride;
#pragma unroll
    for (int i = 0; i < 4; ++i) {
#pragma unroll
        for (int j = 0; j < 4; ++j) {
            int gr = row0 + wm + i * 16 + cr;
            int gc = col0 + wn + j * 16 + m;
            if (gc >= N) continue;
#pragma unroll
            for (int r = 0; r < 4; ++r) {
                float v = acc[i][j][r];
                if (EPI == ME_SOFTPLUS) {
                    v += bias[gc];
                    v = (v > 20.f) ? v : log1pf(__expf(v));
                }
                Cp[(long)(gr + r) * ldc + gc] = v;
            }
        }
    }
}

// ---------------- split-K partial reduction: O = sum_s P[s] ----------------
__global__ __launch_bounds__(256) void reduce_part(
    const float* __restrict__ P, float* __restrict__ O, int n)
{
    int i = (blockIdx.x * 256 + threadIdx.x) * 4;
    if (i >= n) return;
    float4 s = *(const float4*)(P + i);
#pragma unroll
    for (int k = 1; k < 8; ++k) {
        float4 v = *(const float4*)(P + (long)k * n + i);
        s.x += v.x; s.y += v.y; s.z += v.z; s.w += v.w;
    }
    *(float4*)(O + i) = s;
}

// ---------------- causal depthwise conv(4) + bias + SiLU ----------------
__global__ __launch_bounds__(256) void conv_silu(
    const float* __restrict__ xz, const float* __restrict__ w,
    const float* __restrict__ bc, float* __restrict__ U)
{
    int idx = blockIdx.x * 256 + threadIdx.x;       // (b*L + t)*DI + d
    if (idx >= B_ * L_ * DI_) return;
    int d = idx & (DI_ - 1);
    int bt = idx >> 11;
    int t = bt & (L_ - 1);
    float s = bc[d];
#pragma unroll
    for (int j = 0; j < 4; ++j) {
        int tt = t - 3 + j;
        if (tt >= 0)
            s += w[d * 4 + j] * xz[((long)(bt - t + tt)) * (2 * DI_) + d];
    }
    U[idx] = s / (1.f + __expf(-s));                // silu
}

// ---------------- Pass A: per-chunk local scan (CL_=64 steps) ----------------
__global__ __launch_bounds__(256) void scan_chunk(
    const float* __restrict__ U, float* __restrict__ DT,
    const float* __restrict__ XDBL, const float* __restrict__ A_log,
    float* __restrict__ XZ, float* __restrict__ HEND)
{
    const int d = blockIdx.x * 256 + threadIdx.x;
    const int chunk = blockIdx.y;
    const int b = blockIdx.z;
    const int channel = b * DI_ + d;
    const long t0 = (long)b * L_ + chunk * CL_;

    float An[NS_], h[NS_];
#pragma unroll
    for (int n = 0; n < NS_; ++n) {
        An[n] = -__expf(A_log[d * NS_ + n]);
        h[n] = 0.f;
    }
    float sum_dt = 0.f;
    __shared__ float sB[8][NS_], sC[8][NS_];

    for (int tt0 = 0; tt0 < CL_; tt0 += 8) {
        const long bt0 = t0 + tt0;
        {
            int i = threadIdx.x >> 5, j = threadIdx.x & 31;
            float v = XDBL[(bt0 + i) * XPN_ + DTR_ + j];
            if (j < NS_) sB[i][j] = v; else sC[i][j - NS_] = v;
        }
        __syncthreads();
        float u8[8], dt8[8], y8[8], cum8[8];
#pragma unroll
        for (int i = 0; i < 8; ++i) u8[i] = U[(bt0 + i) * DI_ + d];
#pragma unroll
        for (int i = 0; i < 8; ++i) dt8[i] = DT[(bt0 + i) * DI_ + d];
#pragma unroll
        for (int i = 0; i < 8; ++i) {
            const float dt = dt8[i];
            sum_dt += dt;
            cum8[i] = sum_dt;
            const float du = dt * u8[i];
            float y = 0.f;
#pragma unroll
            for (int n = 0; n < NS_; ++n) {
                h[n] = __expf(An[n] * dt) * h[n] + du * sB[i][n];
                y += h[n] * sC[i][n];
            }
            y8[i] = y;
        }
#pragma unroll
        for (int i = 0; i < 8; ++i) XZ[(bt0 + i) * (2 * DI_) + d] = y8[i];
#pragma unroll
        for (int i = 0; i < 8; ++i) DT[(bt0 + i) * DI_ + d] = cum8[i];
        __syncthreads();
    }
#pragma unroll
    for (int n = 0; n < NS_; ++n)
        HEND[(chunk * NS_ + n) * NCH_ + channel] = h[n];
}

// ---------------- Pass B: combine chunk states (in-place) ----------------
__global__ __launch_bounds__(256) void scan_mid(
    const float* __restrict__ DT, const float* __restrict__ A_log,
    float* __restrict__ HST)
{
    const int channel = blockIdx.x * 256 + threadIdx.x;
    const int b = channel / DI_, d = channel % DI_;
    float An[NS_], h0[NS_];
#pragma unroll
    for (int n = 0; n < NS_; ++n) {
        An[n] = -__expf(A_log[d * NS_ + n]);
        h0[n] = 0.f;
    }
    for (int c = 0; c < CH_; ++c) {
        float he[NS_];
#pragma unroll
        for (int n = 0; n < NS_; ++n) {
            he[n] = HST[(c * NS_ + n) * NCH_ + channel];
            HST[(c * NS_ + n) * NCH_ + channel] = h0[n];
        }
        if (c < CH_ - 1) {
            const float S = DT[((long)b * L_ + c * CL_ + CL_ - 1) * DI_ + d];
#pragma unroll
            for (int n = 0; n < NS_; ++n)
                h0[n] = __expf(An[n] * S) * h0[n] + he[n];
        }
    }
}

// ---------------- Pass C: correction + D-skip + z-gating ----------------
__global__ __launch_bounds__(256) void scan_fix(
    const float* __restrict__ U, const float* __restrict__ DT,
    const float* __restrict__ XDBL, const float* __restrict__ A_log,
    const float* __restrict__ Dp, const float* __restrict__ HST,
    float* __restrict__ XZ)
{
    const int d = blockIdx.x * 256 + threadIdx.x;
    const int chunk = blockIdx.y;
    const int b = blockIdx.z;
    const int channel = b * DI_ + d;
    const long t0 = (long)b * L_ + chunk * CL_;

    float An[NS_], h0[NS_];
#pragma unroll
    for (int n = 0; n < NS_; ++n) {
        An[n] = -__expf(A_log[d * NS_ + n]);
        h0[n] = HST[(chunk * NS_ + n) * NCH_ + channel];
    }
    const float Dd = Dp[d];
    __shared__ float sC[8][NS_];

    for (int tt0 = 0; tt0 < CL_; tt0 += 8) {
        const long bt0 = t0 + tt0;
        if (threadIdx.x < 128) {
            int i = threadIdx.x >> 4, n = threadIdx.x & 15;
            sC[i][n] = XDBL[(bt0 + i) * XPN_ + DTR_ + NS_ + n];
        }
        __syncthreads();
        float cum8[8], yp8[8], u8[8], z8[8];
#pragma unroll
        for (int i = 0; i < 8; ++i) cum8[i] = DT[(bt0 + i) * DI_ + d];
#pragma unroll
        for (int i = 0; i < 8; ++i) yp8[i] = XZ[(bt0 + i) * (2 * DI_) + d];
#pragma unroll
        for (int i = 0; i < 8; ++i) u8[i] = U[(bt0 + i) * DI_ + d];
#pragma unroll
        for (int i = 0; i < 8; ++i) z8[i] = XZ[(bt0 + i) * (2 * DI_) + DI_ + d];
#pragma unroll
        for (int i = 0; i < 8; ++i) {
            float corr = 0.f;
#pragma unroll
            for (int n = 0; n < NS_; ++n)
                corr += sC[i][n] * __expf(An[n] * cum8[i]) * h0[n];
            const float y = yp8[i] + corr + u8[i] * Dd;
            const float z = z8[i];
            yp8[i] = y * (z / (1.f + __expf(-z)));
        }
#pragma unroll
        for (int i = 0; i < 8; ++i) XZ[(bt0 + i) * (2 * DI_) + d] = yp8[i];
        __syncthreads();
    }
}

extern "C" void kernel_launch(void* const* d_in, const int* in_sizes, int n_in,
                              void* d_out, int out_size, void* d_ws, size_t ws_size,
                              hipStream_t stream)
{
    const float* x        = (const float*)d_in[0];
    const float* in_proj  = (const float*)d_in[1];
    const float* conv_w   = (const float*)d_in[2];
    const float* conv_b   = (const float*)d_in[3];
    const float* x_proj   = (const float*)d_in[4];
    const float* dt_proj  = (const float*)d_in[5];
    const float* dt_projb = (const float*)d_in[6];
    const float* A_log    = (const float*)d_in[7];
    const float* Dp       = (const float*)d_in[8];
    const float* out_proj = (const float*)d_in[9];

    const int M = B_ * L_;                       // 4096
    float* XZ   = (float*)d_ws;                  // [M, 2*DI]   67 MB
    float* U    = XZ + (size_t)M * 2 * DI_;      // [M, DI]     33.5 MB
    float* XDBL = U + (size_t)M * DI_;           // [M, 160]    2.6 MB
    float* DT   = XDBL + (size_t)M * XPN_;       // [M, DI]     33.5 MB
    // HEND/HST ([CH][NS][NCH] = 8.4 MB) lives in d_out (16.8 MB, dead until
    // GEMM4, which overwrites every element).
    float* HEND = (float*)d_out;

    // --- overlays (disjoint lifetimes) ---
    const int NX = M * DM_;
    const int NO = DM_ * DI_;
    unsigned short* XB = (unsigned short*)U;          // x bf16; dead before conv writes U
    unsigned short* WB = (unsigned short*)DT;         // in_proj bf16; dead after GEMM1
    float* PART = DT;                                 // [8][M][160] = 21 MB, dead after reduce
    unsigned short* YB = (unsigned short*)U;          // y bf16; U dead after scan_fix
    unsigned short* OB = (unsigned short*)DT;         // out_proj bf16; DT dead after scan_fix

    // 1) cast x and in_proj to bf16
    cast_flat<<<NX / 1024, 256, 0, stream>>>(x, XB, NX);
    cast_flat<<<NX / 1024, 256, 0, stream>>>(in_proj, WB, NX);

    // 2) xz = x @ in_proj^T  (MFMA bf16)  [4096 x 4096], K=1024
    gemm_mfma<<<dim3(32, 32), 256, 0, stream>>>(
        XB, DM_, WB, DM_, XZ, 2 * DI_, DM_);

    // 3) u = silu(conv(xb) + b)
    conv_silu<<<(M * DI_ + 255) / 256, 256, 0, stream>>>(XZ, conv_w, conv_b, U);

    // 4) x_dbl = u @ x_proj^T   [4096 x 160], K=2048; split-K x8 -> PART, reduce
    gemm_mf32<ME_PART><<<dim3(2, 32, 8), 256, 0, stream>>>(
        U, DI_, x_proj, DI_, PART, XPN_, nullptr, XPN_, 256, (long)M * XPN_);
    reduce_part<<<(M * XPN_) / 1024, 256, 0, stream>>>(PART, XDBL, M * XPN_);

    // 5) dt = softplus(x_dbl[:, :128] @ dt_proj^T + b)   [4096 x 2048], K=128
    gemm_mf32<ME_SOFTPLUS><<<dim3(16, 32, 1), 256, 0, stream>>>(
        XDBL, XPN_, dt_proj, DTR_, DT, DI_, dt_projb, DI_, DTR_, 0);

    // 6) chunked selective scan (32 chunks of 64; h-state buffer in d_out)
    scan_chunk<<<dim3(8, CH_, B_), 256, 0, stream>>>(U, DT, XDBL, A_log, XZ, HEND);
    scan_mid<<<NCH_ / 256, 256, 0, stream>>>(DT, A_log, HEND);
    scan_fix<<<dim3(8, CH_, B_), 256, 0, stream>>>(U, DT, XDBL, A_log, Dp, HEND, XZ);

    // 7) cast y and out_proj to bf16
    cast_y<<<(M * DI_) / 1024, 256, 0, stream>>>(XZ, YB);
    cast_flat<<<NO / 1024, 256, 0, stream>>>(out_proj, OB, NO);

    // 8) out = y @ out_proj^T  (MFMA bf16)  [4096 x 1024], K=2048
    gemm_mfma<<<dim3(8, 32), 256, 0, stream>>>(
        YB, DI_, OB, DI_, (float*)d_out, DM_, DI_);
}

// Round 8
// 418.343 us; speedup vs baseline: 12.3113x; 1.2642x over previous
//
#include <hip/hip_runtime.h>
#include <hip/hip_bf16.h>
#include <math.h>

// All reference tensors are jnp.float32. GEMMs run in pure bf16 (fp32 acc).

#define B_ 2
#define L_ 2048
#define DM_ 1024
#define DI_ 2048
#define NS_ 16
#define DTR_ 128
#define XPN_ 160   // DTR + 2*NS
#define CH_ 32     // chunks over L
#define CL_ 64     // L / CH_
#define NCH_ 4096  // B_ * DI_

typedef __attribute__((ext_vector_type(8))) short short8;
typedef __attribute__((ext_vector_type(4))) float f32x4;

__device__ inline unsigned short bfbits(float f) {
    __hip_bfloat16 h = __float2bfloat16(f);
    return *reinterpret_cast<unsigned short*>(&h);
}

// ---------------- fp32 -> bf16 cast (flat) ----------------
__global__ __launch_bounds__(256) void cast_flat(
    const float* __restrict__ s, unsigned short* __restrict__ o, int n)
{
    int i = (blockIdx.x * 256 + threadIdx.x) * 4;
    if (i >= n) return;
    float4 v = *(const float4*)(s + i);
    *(ushort4*)(o + i) = make_ushort4(bfbits(v.x), bfbits(v.y), bfbits(v.z), bfbits(v.w));
}

// ---------------- strided cast: y (cols 0..DI-1 of XZ) ----------------
__global__ __launch_bounds__(256) void cast_y(
    const float* __restrict__ XZ, unsigned short* __restrict__ o)
{
    int idx = blockIdx.x * 256 + threadIdx.x;     // over M*DI/4
    int t = idx >> 9;                             // DI_/4 = 512
    int d = (idx & 511) * 4;
    float4 v = *(const float4*)(XZ + (long)t * (2 * DI_) + d);
    long off = (long)t * DI_ + d;
    *(ushort4*)(o + off) = make_ushort4(bfbits(v.x), bfbits(v.y), bfbits(v.z), bfbits(v.w));
}

// ---------------- MFMA bf16 GEMM (pre-cast inputs): C = A @ B^T ----------
// 128x128 block, 4 waves, each wave 64x64 = 4x4 tiles of 16x16, KT=32.
__global__ __launch_bounds__(256) void gemm_mfma(
    const unsigned short* __restrict__ A, int lda,
    const unsigned short* __restrict__ B, int ldb,
    float* __restrict__ C, int ldc, int K)
{
    __shared__ unsigned short sA[128][40];   // pad 32->40
    __shared__ unsigned short sB[128][40];
    const int tid = threadIdx.x;
    const int lane = tid & 63, wave = tid >> 6;
    const int row0 = blockIdx.y * 128, col0 = blockIdx.x * 128;
    const int wm = (wave & 1) << 6, wn = (wave >> 1) << 6;
    const int m = lane & 15;
    const int ko = (lane >> 4) << 3;

    f32x4 acc[4][4];
    const f32x4 zero = {0.f, 0.f, 0.f, 0.f};
#pragma unroll
    for (int i = 0; i < 4; ++i)
#pragma unroll
        for (int j = 0; j < 4; ++j) acc[i][j] = zero;

    for (int k0 = 0; k0 < K; k0 += 32) {
#pragma unroll
        for (int c = 0; c < 2; ++c) {
            int idx = tid + (c << 8);          // 0..511
            int r = idx >> 2;                  // 0..127
            int col8 = (idx & 3) << 3;         // 0,8,16,24
            *(short8*)&sA[r][col8] = *(const short8*)(A + (long)(row0 + r) * lda + k0 + col8);
            *(short8*)&sB[r][col8] = *(const short8*)(B + (long)(col0 + r) * ldb + k0 + col8);
        }
        __syncthreads();

        short8 af[4];
#pragma unroll
        for (int i = 0; i < 4; ++i)
            af[i] = *(const short8*)&sA[wm + i * 16 + m][ko];
#pragma unroll
        for (int j = 0; j < 4; ++j) {
            short8 bf = *(const short8*)&sB[wn + j * 16 + m][ko];
#pragma unroll
            for (int i = 0; i < 4; ++i)
                acc[i][j] = __builtin_amdgcn_mfma_f32_16x16x32_bf16(af[i], bf, acc[i][j], 0, 0, 0);
        }
        __syncthreads();
    }

    const int cr = (lane >> 4) << 2;
#pragma unroll
    for (int i = 0; i < 4; ++i) {
#pragma unroll
        for (int j = 0; j < 4; ++j) {
            int gr = row0 + wm + i * 16 + cr;
            int gc = col0 + wn + j * 16 + m;
#pragma unroll
            for (int r = 0; r < 4; ++r)
                C[(long)(gr + r) * ldc + gc] = acc[i][j][r];
        }
    }
}

// ------- small-K MFMA GEMM, 64x64 tiles, fp32 inputs cast on the fly ------
// C = A @ B^T (+ split-K via blockIdx.z -> C + z*partStride).
// 256 threads = 4 waves; wave w computes rows [w*16, w*16+16) x 64 cols.
// M multiple of 64; N-guarded; kslice multiple of 32.
enum { ME_PART = 0, ME_SOFTPLUS = 1 };

template <int EPI>
__global__ __launch_bounds__(256) void gemm_s64(
    const float* __restrict__ A, int lda,
    const float* __restrict__ B, int ldb,
    float* __restrict__ C, int ldc,
    const float* __restrict__ bias,
    int N, int kslice, long partStride)
{
    __shared__ unsigned short sA[64][40];
    __shared__ unsigned short sB[64][40];
    const int tid = threadIdx.x;
    const int lane = tid & 63, wave = tid >> 6;
    const int row0 = blockIdx.y * 64, col0 = blockIdx.x * 64;
    const int m = lane & 15;
    const int ko = (lane >> 4) << 3;
    const int kbeg = blockIdx.z * kslice;
    const int kend = kbeg + kslice;

    f32x4 acc[4];
    const f32x4 zero = {0.f, 0.f, 0.f, 0.f};
#pragma unroll
    for (int j = 0; j < 4; ++j) acc[j] = zero;

    for (int k0 = kbeg; k0 < kend; k0 += 32) {
        // stage A and B tiles: 64x32 fp32 each = 512 float4s / 256 threads
#pragma unroll
        for (int c = 0; c < 2; ++c) {
            int idx = tid + (c << 8);         // 0..511
            int r = idx >> 3;                 // 0..63
            int c4 = (idx & 7) << 2;          // 0,4,..,28
            float4 v = *(const float4*)(A + (long)(row0 + r) * lda + k0 + c4);
            *(ushort4*)&sA[r][c4] = make_ushort4(bfbits(v.x), bfbits(v.y), bfbits(v.z), bfbits(v.w));
            int gr = col0 + r;
            float4 w = make_float4(0.f, 0.f, 0.f, 0.f);
            if (gr < N) w = *(const float4*)(B + (long)gr * ldb + k0 + c4);
            *(ushort4*)&sB[r][c4] = make_ushort4(bfbits(w.x), bfbits(w.y), bfbits(w.z), bfbits(w.w));
        }
        __syncthreads();

        short8 af = *(const short8*)&sA[(wave << 4) + m][ko];
#pragma unroll
        for (int j = 0; j < 4; ++j) {
            short8 bf = *(const short8*)&sB[j * 16 + m][ko];
            acc[j] = __builtin_amdgcn_mfma_f32_16x16x32_bf16(af, bf, acc[j], 0, 0, 0);
        }
        __syncthreads();
    }

    const int cr = (lane >> 4) << 2;
    const int gr = row0 + (wave << 4) + cr;
    float* Cp = C + (long)blockIdx.z * partStride;
#pragma unroll
    for (int j = 0; j < 4; ++j) {
        int gc = col0 + j * 16 + m;
        if (gc >= N) continue;
#pragma unroll
        for (int r = 0; r < 4; ++r) {
            float v = acc[j][r];
            if (EPI == ME_SOFTPLUS) {
                v += bias[gc];
                v = (v > 20.f) ? v : log1pf(__expf(v));
            }
            Cp[(long)(gr + r) * ldc + gc] = v;
        }
    }
}

// ---------------- split-K partial reduction: O = sum_s P[s] ----------------
__global__ __launch_bounds__(256) void reduce_part(
    const float* __restrict__ P, float* __restrict__ O, int n)
{
    int i = (blockIdx.x * 256 + threadIdx.x) * 4;
    if (i >= n) return;
    float4 s = *(const float4*)(P + i);
#pragma unroll
    for (int k = 1; k < 8; ++k) {
        float4 v = *(const float4*)(P + (long)k * n + i);
        s.x += v.x; s.y += v.y; s.z += v.z; s.w += v.w;
    }
    *(float4*)(O + i) = s;
}

// ---------------- causal depthwise conv(4) + bias + SiLU ----------------
__global__ __launch_bounds__(256) void conv_silu(
    const float* __restrict__ xz, const float* __restrict__ w,
    const float* __restrict__ bc, float* __restrict__ U)
{
    int idx = blockIdx.x * 256 + threadIdx.x;       // (b*L + t)*DI + d
    if (idx >= B_ * L_ * DI_) return;
    int d = idx & (DI_ - 1);
    int bt = idx >> 11;
    int t = bt & (L_ - 1);
    float s = bc[d];
#pragma unroll
    for (int j = 0; j < 4; ++j) {
        int tt = t - 3 + j;
        if (tt >= 0)
            s += w[d * 4 + j] * xz[((long)(bt - t + tt)) * (2 * DI_) + d];
    }
    U[idx] = s / (1.f + __expf(-s));                // silu
}

// ---------------- Pass A: per-chunk local scan (CL_=64 steps) ----------------
__global__ __launch_bounds__(256) void scan_chunk(
    const float* __restrict__ U, float* __restrict__ DT,
    const float* __restrict__ XDBL, const float* __restrict__ A_log,
    float* __restrict__ XZ, float* __restrict__ HEND)
{
    const int d = blockIdx.x * 256 + threadIdx.x;
    const int chunk = blockIdx.y;
    const int b = blockIdx.z;
    const int channel = b * DI_ + d;
    const long t0 = (long)b * L_ + chunk * CL_;

    float An[NS_], h[NS_];
#pragma unroll
    for (int n = 0; n < NS_; ++n) {
        An[n] = -__expf(A_log[d * NS_ + n]);
        h[n] = 0.f;
    }
    float sum_dt = 0.f;
    __shared__ float sB[8][NS_], sC[8][NS_];

    for (int tt0 = 0; tt0 < CL_; tt0 += 8) {
        const long bt0 = t0 + tt0;
        {
            int i = threadIdx.x >> 5, j = threadIdx.x & 31;
            float v = XDBL[(bt0 + i) * XPN_ + DTR_ + j];
            if (j < NS_) sB[i][j] = v; else sC[i][j - NS_] = v;
        }
        __syncthreads();
        float u8[8], dt8[8], y8[8], cum8[8];
#pragma unroll
        for (int i = 0; i < 8; ++i) u8[i] = U[(bt0 + i) * DI_ + d];
#pragma unroll
        for (int i = 0; i < 8; ++i) dt8[i] = DT[(bt0 + i) * DI_ + d];
#pragma unroll
        for (int i = 0; i < 8; ++i) {
            const float dt = dt8[i];
            sum_dt += dt;
            cum8[i] = sum_dt;
            const float du = dt * u8[i];
            float y = 0.f;
#pragma unroll
            for (int n = 0; n < NS_; ++n) {
                h[n] = __expf(An[n] * dt) * h[n] + du * sB[i][n];
                y += h[n] * sC[i][n];
            }
            y8[i] = y;
        }
#pragma unroll
        for (int i = 0; i < 8; ++i) XZ[(bt0 + i) * (2 * DI_) + d] = y8[i];
#pragma unroll
        for (int i = 0; i < 8; ++i) DT[(bt0 + i) * DI_ + d] = cum8[i];
        __syncthreads();
    }
#pragma unroll
    for (int n = 0; n < NS_; ++n)
        HEND[(chunk * NS_ + n) * NCH_ + channel] = h[n];
}

// ---------------- Pass B: combine chunk states (in-place) ----------------
__global__ __launch_bounds__(256) void scan_mid(
    const float* __restrict__ DT, const float* __restrict__ A_log,
    float* __restrict__ HST)
{
    const int channel = blockIdx.x * 256 + threadIdx.x;
    const int b = channel / DI_, d = channel % DI_;
    float An[NS_], h0[NS_];
#pragma unroll
    for (int n = 0; n < NS_; ++n) {
        An[n] = -__expf(A_log[d * NS_ + n]);
        h0[n] = 0.f;
    }
    for (int c = 0; c < CH_; ++c) {
        float he[NS_];
#pragma unroll
        for (int n = 0; n < NS_; ++n) {
            he[n] = HST[(c * NS_ + n) * NCH_ + channel];
            HST[(c * NS_ + n) * NCH_ + channel] = h0[n];
        }
        if (c < CH_ - 1) {
            const float S = DT[((long)b * L_ + c * CL_ + CL_ - 1) * DI_ + d];
#pragma unroll
            for (int n = 0; n < NS_; ++n)
                h0[n] = __expf(An[n] * S) * h0[n] + he[n];
        }
    }
}

// ---------------- Pass C: correction + D-skip + z-gating ----------------
__global__ __launch_bounds__(256) void scan_fix(
    const float* __restrict__ U, const float* __restrict__ DT,
    const float* __restrict__ XDBL, const float* __restrict__ A_log,
    const float* __restrict__ Dp, const float* __restrict__ HST,
    float* __restrict__ XZ)
{
    const int d = blockIdx.x * 256 + threadIdx.x;
    const int chunk = blockIdx.y;
    const int b = blockIdx.z;
    const int channel = b * DI_ + d;
    const long t0 = (long)b * L_ + chunk * CL_;

    float An[NS_], h0[NS_];
#pragma unroll
    for (int n = 0; n < NS_; ++n) {
        An[n] = -__expf(A_log[d * NS_ + n]);
        h0[n] = HST[(chunk * NS_ + n) * NCH_ + channel];
    }
    const float Dd = Dp[d];
    __shared__ float sC[8][NS_];

    for (int tt0 = 0; tt0 < CL_; tt0 += 8) {
        const long bt0 = t0 + tt0;
        if (threadIdx.x < 128) {
            int i = threadIdx.x >> 4, n = threadIdx.x & 15;
            sC[i][n] = XDBL[(bt0 + i) * XPN_ + DTR_ + NS_ + n];
        }
        __syncthreads();
        float cum8[8], yp8[8], u8[8], z8[8];
#pragma unroll
        for (int i = 0; i < 8; ++i) cum8[i] = DT[(bt0 + i) * DI_ + d];
#pragma unroll
        for (int i = 0; i < 8; ++i) yp8[i] = XZ[(bt0 + i) * (2 * DI_) + d];
#pragma unroll
        for (int i = 0; i < 8; ++i) u8[i] = U[(bt0 + i) * DI_ + d];
#pragma unroll
        for (int i = 0; i < 8; ++i) z8[i] = XZ[(bt0 + i) * (2 * DI_) + DI_ + d];
#pragma unroll
        for (int i = 0; i < 8; ++i) {
            float corr = 0.f;
#pragma unroll
            for (int n = 0; n < NS_; ++n)
                corr += sC[i][n] * __expf(An[n] * cum8[i]) * h0[n];
            const float y = yp8[i] + corr + u8[i] * Dd;
            const float z = z8[i];
            yp8[i] = y * (z / (1.f + __expf(-z)));
        }
#pragma unroll
        for (int i = 0; i < 8; ++i) XZ[(bt0 + i) * (2 * DI_) + d] = yp8[i];
        __syncthreads();
    }
}

extern "C" void kernel_launch(void* const* d_in, const int* in_sizes, int n_in,
                              void* d_out, int out_size, void* d_ws, size_t ws_size,
                              hipStream_t stream)
{
    const float* x        = (const float*)d_in[0];
    const float* in_proj  = (const float*)d_in[1];
    const float* conv_w   = (const float*)d_in[2];
    const float* conv_b   = (const float*)d_in[3];
    const float* x_proj   = (const float*)d_in[4];
    const float* dt_proj  = (const float*)d_in[5];
    const float* dt_projb = (const float*)d_in[6];
    const float* A_log    = (const float*)d_in[7];
    const float* Dp       = (const float*)d_in[8];
    const float* out_proj = (const float*)d_in[9];

    const int M = B_ * L_;                       // 4096
    float* XZ   = (float*)d_ws;                  // [M, 2*DI]   67 MB
    float* U    = XZ + (size_t)M * 2 * DI_;      // [M, DI]     33.5 MB
    float* XDBL = U + (size_t)M * DI_;           // [M, 160]    2.6 MB
    float* DT   = XDBL + (size_t)M * XPN_;       // [M, DI]     33.5 MB
    // HEND/HST ([CH][NS][NCH] = 8.4 MB) lives in d_out (16.8 MB, dead until
    // GEMM4, which overwrites every element).
    float* HEND = (float*)d_out;

    // --- overlays (disjoint lifetimes) ---
    const int NX = M * DM_;
    const int NO = DM_ * DI_;
    unsigned short* XB = (unsigned short*)U;          // x bf16; dead before conv writes U
    unsigned short* WB = (unsigned short*)DT;         // in_proj bf16; dead after GEMM1
    float* PART = DT;                                 // [8][M][160] = 21 MB, dead after reduce
    unsigned short* YB = (unsigned short*)U;          // y bf16; U dead after scan_fix
    unsigned short* OB = (unsigned short*)DT;         // out_proj bf16; DT dead after scan_fix

    // 1) cast x and in_proj to bf16
    cast_flat<<<NX / 1024, 256, 0, stream>>>(x, XB, NX);
    cast_flat<<<NX / 1024, 256, 0, stream>>>(in_proj, WB, NX);

    // 2) xz = x @ in_proj^T  (MFMA bf16)  [4096 x 4096], K=1024
    gemm_mfma<<<dim3(32, 32), 256, 0, stream>>>(
        XB, DM_, WB, DM_, XZ, 2 * DI_, DM_);

    // 3) u = silu(conv(xb) + b)
    conv_silu<<<(M * DI_ + 255) / 256, 256, 0, stream>>>(XZ, conv_w, conv_b, U);

    // 4) x_dbl = u @ x_proj^T   [4096 x 160], K=2048; split-K x8, 64x64 tiles
    gemm_s64<ME_PART><<<dim3(3, 64, 8), 256, 0, stream>>>(
        U, DI_, x_proj, DI_, PART, XPN_, nullptr, XPN_, 256, (long)M * XPN_);
    reduce_part<<<(M * XPN_) / 1024, 256, 0, stream>>>(PART, XDBL, M * XPN_);

    // 5) dt = softplus(x_dbl[:, :128] @ dt_proj^T + b)  [4096 x 2048], K=128
    gemm_s64<ME_SOFTPLUS><<<dim3(32, 64, 1), 256, 0, stream>>>(
        XDBL, XPN_, dt_proj, DTR_, DT, DI_, dt_projb, DI_, DTR_, 0);

    // 6) chunked selective scan (32 chunks of 64; h-state buffer in d_out)
    scan_chunk<<<dim3(8, CH_, B_), 256, 0, stream>>>(U, DT, XDBL, A_log, XZ, HEND);
    scan_mid<<<NCH_ / 256, 256, 0, stream>>>(DT, A_log, HEND);
    scan_fix<<<dim3(8, CH_, B_), 256, 0, stream>>>(U, DT, XDBL, A_log, Dp, HEND, XZ);

    // 7) cast y and out_proj to bf16
    cast_y<<<(M * DI_) / 1024, 256, 0, stream>>>(XZ, YB);
    cast_flat<<<NO / 1024, 256, 0, stream>>>(out_proj, OB, NO);

    // 8) out = y @ out_proj^T  (MFMA bf16)  [4096 x 1024], K=2048
    gemm_mfma<<<dim3(8, 32), 256, 0, stream>>>(
        YB, DI_, OB, DI_, (float*)d_out, DM_, DI_);
}

// Round 9
// 405.184 us; speedup vs baseline: 12.7111x; 1.0325x over previous
//
#include <hip/hip_runtime.h>
#include <hip/hip_bf16.h>
#include <math.h>

// All reference tensors are jnp.float32. GEMMs run in pure bf16 (fp32 acc).

#define B_ 2
#define L_ 2048
#define DM_ 1024
#define DI_ 2048
#define NS_ 16
#define DTR_ 128
#define XPN_ 160   // DTR + 2*NS
#define CH_ 32     // chunks over L
#define CL_ 64     // L / CH_
#define NCH_ 4096  // B_ * DI_

typedef __attribute__((ext_vector_type(8))) short short8;
typedef __attribute__((ext_vector_type(4))) float f32x4;

__device__ inline unsigned short bfbits(float f) {
    __hip_bfloat16 h = __float2bfloat16(f);
    return *reinterpret_cast<unsigned short*>(&h);
}

// ---------------- fused pair cast: fp32 -> bf16 (two equal-size arrays) ----
__global__ __launch_bounds__(256) void cast_pair(
    const float* __restrict__ s0, unsigned short* __restrict__ d0,
    const float* __restrict__ s1, unsigned short* __restrict__ d1, int nper)
{
    int i = (blockIdx.x * 256 + threadIdx.x) * 4;
    const float* s = s0;
    unsigned short* d = d0;
    if (i >= nper) { s = s1; d = d1; i -= nper; }
    float4 v = *(const float4*)(s + i);
    *(ushort4*)(d + i) = make_ushort4(bfbits(v.x), bfbits(v.y), bfbits(v.z), bfbits(v.w));
}

// -------- fused cast: y (strided out of XZ) + out_proj (flat) -> bf16 -----
__global__ __launch_bounds__(256) void cast_y_op(
    const float* __restrict__ XZ, unsigned short* __restrict__ yb,
    const float* __restrict__ op, unsigned short* __restrict__ ob, int ny4)
{
    int idx = blockIdx.x * 256 + threadIdx.x;
    if (idx < ny4) {                              // y: cols 0..DI-1 of XZ
        int t = idx >> 9;                         // DI_/4 = 512
        int d = (idx & 511) * 4;
        float4 v = *(const float4*)(XZ + (long)t * (2 * DI_) + d);
        long off = (long)t * DI_ + d;
        *(ushort4*)(yb + off) = make_ushort4(bfbits(v.x), bfbits(v.y), bfbits(v.z), bfbits(v.w));
    } else {                                      // out_proj flat
        int i = (idx - ny4) * 4;
        float4 v = *(const float4*)(op + i);
        *(ushort4*)(ob + i) = make_ushort4(bfbits(v.x), bfbits(v.y), bfbits(v.z), bfbits(v.w));
    }
}

// ---------------- MFMA bf16 GEMM (pre-cast inputs): C = A @ B^T ----------
// 128x128 block, 4 waves, each wave 64x64 = 4x4 tiles of 16x16, KT=32.
__global__ __launch_bounds__(256) void gemm_mfma(
    const unsigned short* __restrict__ A, int lda,
    const unsigned short* __restrict__ B, int ldb,
    float* __restrict__ C, int ldc, int K)
{
    __shared__ unsigned short sA[128][40];   // pad 32->40
    __shared__ unsigned short sB[128][40];
    const int tid = threadIdx.x;
    const int lane = tid & 63, wave = tid >> 6;
    const int row0 = blockIdx.y * 128, col0 = blockIdx.x * 128;
    const int wm = (wave & 1) << 6, wn = (wave >> 1) << 6;
    const int m = lane & 15;
    const int ko = (lane >> 4) << 3;

    f32x4 acc[4][4];
    const f32x4 zero = {0.f, 0.f, 0.f, 0.f};
#pragma unroll
    for (int i = 0; i < 4; ++i)
#pragma unroll
        for (int j = 0; j < 4; ++j) acc[i][j] = zero;

    for (int k0 = 0; k0 < K; k0 += 32) {
#pragma unroll
        for (int c = 0; c < 2; ++c) {
            int idx = tid + (c << 8);          // 0..511
            int r = idx >> 2;                  // 0..127
            int col8 = (idx & 3) << 3;         // 0,8,16,24
            *(short8*)&sA[r][col8] = *(const short8*)(A + (long)(row0 + r) * lda + k0 + col8);
            *(short8*)&sB[r][col8] = *(const short8*)(B + (long)(col0 + r) * ldb + k0 + col8);
        }
        __syncthreads();

        short8 af[4];
#pragma unroll
        for (int i = 0; i < 4; ++i)
            af[i] = *(const short8*)&sA[wm + i * 16 + m][ko];
#pragma unroll
        for (int j = 0; j < 4; ++j) {
            short8 bf = *(const short8*)&sB[wn + j * 16 + m][ko];
#pragma unroll
            for (int i = 0; i < 4; ++i)
                acc[i][j] = __builtin_amdgcn_mfma_f32_16x16x32_bf16(af[i], bf, acc[i][j], 0, 0, 0);
        }
        __syncthreads();
    }

    const int cr = (lane >> 4) << 2;
#pragma unroll
    for (int i = 0; i < 4; ++i) {
#pragma unroll
        for (int j = 0; j < 4; ++j) {
            int gr = row0 + wm + i * 16 + cr;
            int gc = col0 + wn + j * 16 + m;
#pragma unroll
            for (int r = 0; r < 4; ++r)
                C[(long)(gr + r) * ldc + gc] = acc[i][j][r];
        }
    }
}

// ------- 64x64-tile bf16 GEMM (pre-cast inputs), high-grid variant --------
// 256 threads = 4 waves; wave w: rows [w*16, w*16+16) x 64 cols.
__global__ __launch_bounds__(256) void gemm_b64(
    const unsigned short* __restrict__ A, int lda,
    const unsigned short* __restrict__ B, int ldb,
    float* __restrict__ C, int ldc, int K)
{
    __shared__ unsigned short sA[64][40];
    __shared__ unsigned short sB[64][40];
    const int tid = threadIdx.x;
    const int lane = tid & 63, wave = tid >> 6;
    const int row0 = blockIdx.y * 64, col0 = blockIdx.x * 64;
    const int m = lane & 15;
    const int ko = (lane >> 4) << 3;

    f32x4 acc[4];
    const f32x4 zero = {0.f, 0.f, 0.f, 0.f};
#pragma unroll
    for (int j = 0; j < 4; ++j) acc[j] = zero;

    for (int k0 = 0; k0 < K; k0 += 32) {
        int r = tid >> 2;                  // 0..63
        int c8 = (tid & 3) << 3;           // 0,8,16,24
        *(short8*)&sA[r][c8] = *(const short8*)(A + (long)(row0 + r) * lda + k0 + c8);
        *(short8*)&sB[r][c8] = *(const short8*)(B + (long)(col0 + r) * ldb + k0 + c8);
        __syncthreads();

        short8 af = *(const short8*)&sA[(wave << 4) + m][ko];
#pragma unroll
        for (int j = 0; j < 4; ++j) {
            short8 bf = *(const short8*)&sB[j * 16 + m][ko];
            acc[j] = __builtin_amdgcn_mfma_f32_16x16x32_bf16(af, bf, acc[j], 0, 0, 0);
        }
        __syncthreads();
    }

    const int cr = (lane >> 4) << 2;
    const int gr = row0 + (wave << 4) + cr;
#pragma unroll
    for (int j = 0; j < 4; ++j) {
        int gc = col0 + j * 16 + m;
#pragma unroll
        for (int r = 0; r < 4; ++r)
            C[(long)(gr + r) * ldc + gc] = acc[j][r];
    }
}

// ------- small-K MFMA GEMM, 64x64 tiles, fp32 inputs cast on the fly ------
enum { ME_PART = 0, ME_SOFTPLUS = 1 };

template <int EPI>
__global__ __launch_bounds__(256) void gemm_s64(
    const float* __restrict__ A, int lda,
    const float* __restrict__ B, int ldb,
    float* __restrict__ C, int ldc,
    const float* __restrict__ bias,
    int N, int kslice, long partStride)
{
    __shared__ unsigned short sA[64][40];
    __shared__ unsigned short sB[64][40];
    const int tid = threadIdx.x;
    const int lane = tid & 63, wave = tid >> 6;
    const int row0 = blockIdx.y * 64, col0 = blockIdx.x * 64;
    const int m = lane & 15;
    const int ko = (lane >> 4) << 3;
    const int kbeg = blockIdx.z * kslice;
    const int kend = kbeg + kslice;

    f32x4 acc[4];
    const f32x4 zero = {0.f, 0.f, 0.f, 0.f};
#pragma unroll
    for (int j = 0; j < 4; ++j) acc[j] = zero;

    for (int k0 = kbeg; k0 < kend; k0 += 32) {
#pragma unroll
        for (int c = 0; c < 2; ++c) {
            int idx = tid + (c << 8);         // 0..511
            int r = idx >> 3;                 // 0..63
            int c4 = (idx & 7) << 2;          // 0,4,..,28
            float4 v = *(const float4*)(A + (long)(row0 + r) * lda + k0 + c4);
            *(ushort4*)&sA[r][c4] = make_ushort4(bfbits(v.x), bfbits(v.y), bfbits(v.z), bfbits(v.w));
            int gr = col0 + r;
            float4 w = make_float4(0.f, 0.f, 0.f, 0.f);
            if (gr < N) w = *(const float4*)(B + (long)gr * ldb + k0 + c4);
            *(ushort4*)&sB[r][c4] = make_ushort4(bfbits(w.x), bfbits(w.y), bfbits(w.z), bfbits(w.w));
        }
        __syncthreads();

        short8 af = *(const short8*)&sA[(wave << 4) + m][ko];
#pragma unroll
        for (int j = 0; j < 4; ++j) {
            short8 bf = *(const short8*)&sB[j * 16 + m][ko];
            acc[j] = __builtin_amdgcn_mfma_f32_16x16x32_bf16(af, bf, acc[j], 0, 0, 0);
        }
        __syncthreads();
    }

    const int cr = (lane >> 4) << 2;
    const int gr = row0 + (wave << 4) + cr;
    float* Cp = C + (long)blockIdx.z * partStride;
#pragma unroll
    for (int j = 0; j < 4; ++j) {
        int gc = col0 + j * 16 + m;
        if (gc >= N) continue;
#pragma unroll
        for (int r = 0; r < 4; ++r) {
            float v = acc[j][r];
            if (EPI == ME_SOFTPLUS) {
                v += bias[gc];
                v = (v > 20.f) ? v : log1pf(__expf(v));
            }
            Cp[(long)(gr + r) * ldc + gc] = v;
        }
    }
}

// ---------------- split-K partial reduction: O = sum_s P[s] ----------------
__global__ __launch_bounds__(256) void reduce_part(
    const float* __restrict__ P, float* __restrict__ O, int n)
{
    int i = (blockIdx.x * 256 + threadIdx.x) * 4;
    if (i >= n) return;
    float4 s = *(const float4*)(P + i);
#pragma unroll
    for (int k = 1; k < 8; ++k) {
        float4 v = *(const float4*)(P + (long)k * n + i);
        s.x += v.x; s.y += v.y; s.z += v.z; s.w += v.w;
    }
    *(float4*)(O + i) = s;
}

// ---------------- causal depthwise conv(4) + bias + SiLU ----------------
__global__ __launch_bounds__(256) void conv_silu(
    const float* __restrict__ xz, const float* __restrict__ w,
    const float* __restrict__ bc, float* __restrict__ U)
{
    int idx = blockIdx.x * 256 + threadIdx.x;       // (b*L + t)*DI + d
    if (idx >= B_ * L_ * DI_) return;
    int d = idx & (DI_ - 1);
    int bt = idx >> 11;
    int t = bt & (L_ - 1);
    float s = bc[d];
#pragma unroll
    for (int j = 0; j < 4; ++j) {
        int tt = t - 3 + j;
        if (tt >= 0)
            s += w[d * 4 + j] * xz[((long)(bt - t + tt)) * (2 * DI_) + d];
    }
    U[idx] = s / (1.f + __expf(-s));                // silu
}

// ---------------- Pass A: per-chunk h_end + dt-sum only --------------------
// No y / cum writes. HEND[c][n][ch] = chunk-final state; SDT[c][ch] = sum dt.
__global__ __launch_bounds__(256) void scan_head(
    const float* __restrict__ U, const float* __restrict__ DT,
    const float* __restrict__ XDBL, const float* __restrict__ A_log,
    float* __restrict__ HEND, float* __restrict__ SDT)
{
    const int d = blockIdx.x * 256 + threadIdx.x;
    const int chunk = blockIdx.y;
    const int b = blockIdx.z;
    const int channel = b * DI_ + d;
    const long t0 = (long)b * L_ + chunk * CL_;

    float An[NS_], h[NS_];
#pragma unroll
    for (int n = 0; n < NS_; ++n) {
        An[n] = -__expf(A_log[d * NS_ + n]);
        h[n] = 0.f;
    }
    float sum_dt = 0.f;
    __shared__ float sB[8][NS_];

    for (int tt0 = 0; tt0 < CL_; tt0 += 8) {
        const long bt0 = t0 + tt0;
        if (threadIdx.x < 128) {
            int i = threadIdx.x >> 4, j = threadIdx.x & 15;
            sB[i][j] = XDBL[(bt0 + i) * XPN_ + DTR_ + j];
        }
        __syncthreads();
        float u8[8], dt8[8];
#pragma unroll
        for (int i = 0; i < 8; ++i) u8[i] = U[(bt0 + i) * DI_ + d];
#pragma unroll
        for (int i = 0; i < 8; ++i) dt8[i] = DT[(bt0 + i) * DI_ + d];
#pragma unroll
        for (int i = 0; i < 8; ++i) {
            const float dt = dt8[i];
            sum_dt += dt;
            const float du = dt * u8[i];
#pragma unroll
            for (int n = 0; n < NS_; ++n)
                h[n] = __expf(An[n] * dt) * h[n] + du * sB[i][n];
        }
        __syncthreads();
    }
#pragma unroll
    for (int n = 0; n < NS_; ++n)
        HEND[(chunk * NS_ + n) * NCH_ + channel] = h[n];
    SDT[chunk * NCH_ + channel] = sum_dt;
}

// ---------------- Pass B: combine chunk states (in-place) ----------------
__global__ __launch_bounds__(256) void scan_mid(
    const float* __restrict__ SDT, const float* __restrict__ A_log,
    float* __restrict__ HST)
{
    const int channel = blockIdx.x * 256 + threadIdx.x;
    const int d = channel & (DI_ - 1);
    float An[NS_], h0[NS_];
#pragma unroll
    for (int n = 0; n < NS_; ++n) {
        An[n] = -__expf(A_log[d * NS_ + n]);
        h0[n] = 0.f;
    }
    for (int c = 0; c < CH_; ++c) {
        float he[NS_];
#pragma unroll
        for (int n = 0; n < NS_; ++n) {
            he[n] = HST[(c * NS_ + n) * NCH_ + channel];
            HST[(c * NS_ + n) * NCH_ + channel] = h0[n];
        }
        if (c < CH_ - 1) {
            const float S = SDT[c * NCH_ + channel];
#pragma unroll
            for (int n = 0; n < NS_; ++n)
                h0[n] = __expf(An[n] * S) * h0[n] + he[n];
        }
    }
}

// ---------------- Pass C: full recurrence from h_start + gate --------------
// Exact sequential semantics: h seeded with h_start, y computed directly.
__global__ __launch_bounds__(256) void scan_tail(
    const float* __restrict__ U, const float* __restrict__ DT,
    const float* __restrict__ XDBL, const float* __restrict__ A_log,
    const float* __restrict__ Dp, const float* __restrict__ HST,
    float* __restrict__ XZ)
{
    const int d = blockIdx.x * 256 + threadIdx.x;
    const int chunk = blockIdx.y;
    const int b = blockIdx.z;
    const int channel = b * DI_ + d;
    const long t0 = (long)b * L_ + chunk * CL_;

    float An[NS_], h[NS_];
#pragma unroll
    for (int n = 0; n < NS_; ++n) {
        An[n] = -__expf(A_log[d * NS_ + n]);
        h[n] = HST[(chunk * NS_ + n) * NCH_ + channel];
    }
    const float Dd = Dp[d];
    __shared__ float sB[8][NS_], sC[8][NS_];

    for (int tt0 = 0; tt0 < CL_; tt0 += 8) {
        const long bt0 = t0 + tt0;
        {
            int i = threadIdx.x >> 5, j = threadIdx.x & 31;
            float v = XDBL[(bt0 + i) * XPN_ + DTR_ + j];
            if (j < NS_) sB[i][j] = v; else sC[i][j - NS_] = v;
        }
        __syncthreads();
        float u8[8], dt8[8], z8[8], y8[8];
#pragma unroll
        for (int i = 0; i < 8; ++i) u8[i] = U[(bt0 + i) * DI_ + d];
#pragma unroll
        for (int i = 0; i < 8; ++i) dt8[i] = DT[(bt0 + i) * DI_ + d];
#pragma unroll
        for (int i = 0; i < 8; ++i) z8[i] = XZ[(bt0 + i) * (2 * DI_) + DI_ + d];
#pragma unroll
        for (int i = 0; i < 8; ++i) {
            const float dt = dt8[i];
            const float du = dt * u8[i];
            float y = 0.f;
#pragma unroll
            for (int n = 0; n < NS_; ++n) {
                h[n] = __expf(An[n] * dt) * h[n] + du * sB[i][n];
                y += h[n] * sC[i][n];
            }
            y += u8[i] * Dd;
            const float z = z8[i];
            y8[i] = y * (z / (1.f + __expf(-z)));
        }
#pragma unroll
        for (int i = 0; i < 8; ++i) XZ[(bt0 + i) * (2 * DI_) + d] = y8[i];
        __syncthreads();
    }
}

extern "C" void kernel_launch(void* const* d_in, const int* in_sizes, int n_in,
                              void* d_out, int out_size, void* d_ws, size_t ws_size,
                              hipStream_t stream)
{
    const float* x        = (const float*)d_in[0];
    const float* in_proj  = (const float*)d_in[1];
    const float* conv_w   = (const float*)d_in[2];
    const float* conv_b   = (const float*)d_in[3];
    const float* x_proj   = (const float*)d_in[4];
    const float* dt_proj  = (const float*)d_in[5];
    const float* dt_projb = (const float*)d_in[6];
    const float* A_log    = (const float*)d_in[7];
    const float* Dp       = (const float*)d_in[8];
    const float* out_proj = (const float*)d_in[9];

    const int M = B_ * L_;                       // 4096
    float* XZ   = (float*)d_ws;                  // [M, 2*DI]   67 MB
    float* U    = XZ + (size_t)M * 2 * DI_;      // [M, DI]     33.5 MB
    float* XDBL = U + (size_t)M * DI_;           // [M, 160]    2.6 MB
    float* DT   = XDBL + (size_t)M * XPN_;       // [M, DI]     33.5 MB
    float* SDT  = DT + (size_t)M * DI_;          // [CH][NCH]   0.5 MB
    // HEND/HST ([CH][NS][NCH] = 8.4 MB) lives in d_out (16.8 MB, dead until
    // GEMM4, which overwrites every element).
    float* HEND = (float*)d_out;

    // --- overlays (disjoint lifetimes) ---
    const int NX = M * DM_;
    const int NO = DM_ * DI_;
    unsigned short* XB = (unsigned short*)U;          // x bf16; dead before conv writes U
    unsigned short* WB = (unsigned short*)DT;         // in_proj bf16; dead after GEMM1
    float* PART = DT;                                 // [8][M][160] = 21 MB, dead after reduce
    unsigned short* YB = (unsigned short*)U;          // y bf16; U dead after scan_tail
    unsigned short* OB = (unsigned short*)DT;         // out_proj bf16; DT dead after scan_tail

    // 1) cast x and in_proj to bf16 (single fused launch)
    cast_pair<<<2 * NX / 1024, 256, 0, stream>>>(x, XB, in_proj, WB, NX);

    // 2) xz = x @ in_proj^T  (MFMA bf16)  [4096 x 4096], K=1024
    gemm_mfma<<<dim3(32, 32), 256, 0, stream>>>(
        XB, DM_, WB, DM_, XZ, 2 * DI_, DM_);

    // 3) u = silu(conv(xb) + b)
    conv_silu<<<(M * DI_ + 255) / 256, 256, 0, stream>>>(XZ, conv_w, conv_b, U);

    // 4) x_dbl = u @ x_proj^T   [4096 x 160], K=2048; split-K x8, 64x64 tiles
    gemm_s64<ME_PART><<<dim3(3, 64, 8), 256, 0, stream>>>(
        U, DI_, x_proj, DI_, PART, XPN_, nullptr, XPN_, 256, (long)M * XPN_);
    reduce_part<<<(M * XPN_) / 1024, 256, 0, stream>>>(PART, XDBL, M * XPN_);

    // 5) dt = softplus(x_dbl[:, :128] @ dt_proj^T + b)  [4096 x 2048], K=128
    gemm_s64<ME_SOFTPLUS><<<dim3(32, 64, 1), 256, 0, stream>>>(
        XDBL, XPN_, dt_proj, DTR_, DT, DI_, dt_projb, DI_, DTR_, 0);

    // 6) chunked selective scan: head (h_end+dtsum) -> mid -> tail (exact
    //    recurrence from h_start, fused D-skip + gating; y into XZ y-cols)
    scan_head<<<dim3(8, CH_, B_), 256, 0, stream>>>(U, DT, XDBL, A_log, HEND, SDT);
    scan_mid<<<NCH_ / 256, 256, 0, stream>>>(SDT, A_log, HEND);
    scan_tail<<<dim3(8, CH_, B_), 256, 0, stream>>>(U, DT, XDBL, A_log, Dp, HEND, XZ);

    // 7) cast y + out_proj to bf16 (single fused launch)
    cast_y_op<<<(M * DI_ / 4 + NO / 4) / 256, 256, 0, stream>>>(
        XZ, YB, out_proj, OB, M * DI_ / 4);

    // 8) out = y @ out_proj^T  (64x64 bf16, 1024 blocks)  [4096 x 1024], K=2048
    gemm_b64<<<dim3(16, 64), 256, 0, stream>>>(
        YB, DI_, OB, DI_, (float*)d_out, DM_, DI_);
}